// Round 1
// baseline (2945.741 us; speedup 1.0000x reference)
//
#include <hip/hip_runtime.h>
#include <math.h>

// ---------------------------------------------------------------------------
// ImageTriplaneGenerator — round 1: correctness-first f32, algebraically
// restructured attention (16x FLOP reduction vs materializing K/V):
//   scores[n,h,l] = sum_c ctx[n,l,c] * qk[n,h,c] + qbk[n,h],
//     qk[n,h,:]   = Wk_h^T qn[n,h,:]          (GEMM, BT flavor)
//   out[n,h,:]    = Wv_h^T wctx[n,h,:] + bv_h (GEMM, NN flavor)
//     wctx[n,h,:] = sum_l softmax_l(scores) * ctx[n,l,:]
// Pipeline per plane: build_q (bilinear other-plane means + layernorm) ->
// GEMM qk -> fused sample+attn (ctx in LDS) -> GEMM out.
// ---------------------------------------------------------------------------

constexpr int kG = 64, kS = 4, kC = 771, kNV = 4;
constexpr int kQD = 2313;           // 3 * kC
constexpr int kNPIX = 4096;         // kG * kG
constexpr int kL = 16;              // kS * kNV
constexpr int kImgMStride = kC * kG * kG;  // 3158016, same in both layouts

// ---- tiny 4x4 batched inverse (c2w -> w2c), Gauss-Jordan w/ pivoting ------
__global__ void invert4_kernel(const float* __restrict__ c2w,
                               float* __restrict__ w2c) {
  const int m = threadIdx.x;
  if (m >= kNV) return;
  float a[4][8];
  for (int r = 0; r < 4; ++r)
    for (int c = 0; c < 4; ++c) {
      a[r][c] = c2w[m * 16 + r * 4 + c];
      a[r][4 + c] = (r == c) ? 1.f : 0.f;
    }
  for (int col = 0; col < 4; ++col) {
    int piv = col;
    float best = fabsf(a[col][col]);
    for (int r = col + 1; r < 4; ++r) {
      float t = fabsf(a[r][col]);
      if (t > best) { best = t; piv = r; }
    }
    if (piv != col)
      for (int c = 0; c < 8; ++c) {
        float t = a[col][c]; a[col][c] = a[piv][c]; a[piv][c] = t;
      }
    const float inv = 1.f / a[col][col];
    for (int c = 0; c < 8; ++c) a[col][c] *= inv;
    for (int r = 0; r < 4; ++r)
      if (r != col) {
        const float f = a[r][col];
        for (int c = 0; c < 8; ++c) a[r][c] -= f * a[col][c];
      }
  }
  for (int r = 0; r < 4; ++r)
    for (int c = 0; c < 4; ++c) w2c[m * 16 + r * 4 + c] = a[r][4 + c];
}

// ---- image feature transpose [NV,C,H,W] -> [NV,H,W,C] for coalesced c-reads
__global__ void __launch_bounds__(256) transpose_img_kernel(
    const float* __restrict__ img, float* __restrict__ out) {
  __shared__ float t[64][65];
  const int y = blockIdx.x, m = blockIdx.y, tid = threadIdx.x;
  for (int c0 = 0; c0 < kC; c0 += 64) {
    const int cw = (kC - c0) < 64 ? (kC - c0) : 64;
    for (int idx = tid; idx < cw * 64; idx += 256) {
      const int cl = idx >> 6, x = idx & 63;
      t[cl][x] = img[(((size_t)m * kC + c0 + cl) * 64 + y) * 64 + x];
    }
    __syncthreads();
    for (int idx = tid; idx < 64 * 64; idx += 256) {
      const int x = idx >> 6, cl = idx & 63;
      if (cl < cw)
        out[(((size_t)m * 64 + y) * 64 + x) * (size_t)kC + c0 + cl] = t[cl][x];
    }
    __syncthreads();
  }
}

// ---- build query: part0 copy + 2 other-plane bilinear means, layernorm ----
// Faithful to reference quirk: pixel-range coords passed as "normalized" to a
// second (gx+1)*0.5*(W-1) transform, border padding.
__global__ void __launch_bounds__(256) build_q_kernel(
    const float* __restrict__ qp, const float* __restrict__ qo0,
    const float* __restrict__ qo1, const int plane,
    const float* __restrict__ ln_g, const float* __restrict__ ln_b,
    const float* __restrict__ bk, float* __restrict__ qn,
    float* __restrict__ qbk) {
  const int n = blockIdx.x, i = n >> 6, j = n & 63, tid = threadIdx.x;
  __shared__ float qf[kQD];
  __shared__ int sIdx[2][4][4];
  __shared__ float sW[2][4][4];
  __shared__ float red[16];

  if (tid < 8) {
    const int part = tid >> 2, s = tid & 3;
    const float Xi = -1.f + 2.f * i / 63.f;
    const float Xj = -1.f + 2.f * j / 63.f;
    const float Ts = -1.f + 2.f * s / 3.f;
    float a, b;
    if (plane == 0) { a = part ? Xi : Xj; b = Ts; }           // others: xz,yz
    else if (plane == 1) {                                    // others: xy,yz
      if (part == 0) { a = Xj; b = Ts; } else { a = Ts; b = Xi; }
    } else { a = Ts; b = part ? Xi : Xj; }                    // others: xy,xz
    const float ga = fminf(fmaxf((a * 0.5f + 0.5f) * 63.f, 0.f), 63.f);
    const float gb = fminf(fmaxf((b * 0.5f + 0.5f) * 63.f, 0.f), 63.f);
    const float ix = fminf(fmaxf((ga + 1.f) * 0.5f * 63.f, 0.f), 63.f);
    const float iy = fminf(fmaxf((gb + 1.f) * 0.5f * 63.f, 0.f), 63.f);
    const float x0 = floorf(ix), y0 = floorf(iy);
    const float wx = ix - x0, wy = iy - y0;
    const int x0i = (int)x0, y0i = (int)y0;   // ix,iy already in [0,63]
    const int x1i = (x0i + 1 > 63) ? 63 : x0i + 1;
    const int y1i = (y0i + 1 > 63) ? 63 : y0i + 1;
    sIdx[part][s][0] = (y0i * 64 + x0i) * kC;
    sIdx[part][s][1] = (y0i * 64 + x1i) * kC;
    sIdx[part][s][2] = (y1i * 64 + x0i) * kC;
    sIdx[part][s][3] = (y1i * 64 + x1i) * kC;
    sW[part][s][0] = (1.f - wx) * (1.f - wy);
    sW[part][s][1] = wx * (1.f - wy);
    sW[part][s][2] = (1.f - wx) * wy;
    sW[part][s][3] = wx * wy;
  }
  __syncthreads();

  for (int c = tid; c < kC; c += 256) {
    qf[c] = qp[(size_t)n * kC + c];
    float a1 = 0.f, a2 = 0.f;
#pragma unroll
    for (int s = 0; s < 4; ++s) {
      a1 += qo0[sIdx[0][s][0] + c] * sW[0][s][0]
          + qo0[sIdx[0][s][1] + c] * sW[0][s][1]
          + qo0[sIdx[0][s][2] + c] * sW[0][s][2]
          + qo0[sIdx[0][s][3] + c] * sW[0][s][3];
      a2 += qo1[sIdx[1][s][0] + c] * sW[1][s][0]
          + qo1[sIdx[1][s][1] + c] * sW[1][s][1]
          + qo1[sIdx[1][s][2] + c] * sW[1][s][2]
          + qo1[sIdx[1][s][3] + c] * sW[1][s][3];
    }
    qf[kC + c] = a1 * 0.25f;
    qf[2 * kC + c] = a2 * 0.25f;
  }
  __syncthreads();

  // layernorm over 2313 (two-pass)
  float sm = 0.f;
  for (int idx = tid; idx < kQD; idx += 256) sm += qf[idx];
#pragma unroll
  for (int off = 32; off; off >>= 1) sm += __shfl_down(sm, off);
  if ((tid & 63) == 0) red[tid >> 6] = sm;
  __syncthreads();
  const float mu = (red[0] + red[1] + red[2] + red[3]) * (1.f / kQD);
  __syncthreads();
  float sq = 0.f;
  for (int idx = tid; idx < kQD; idx += 256) {
    const float d = qf[idx] - mu;
    sq += d * d;
  }
#pragma unroll
  for (int off = 32; off; off >>= 1) sq += __shfl_down(sq, off);
  if ((tid & 63) == 0) red[tid >> 6] = sq;
  __syncthreads();
  const float var = (red[0] + red[1] + red[2] + red[3]) * (1.f / kQD);
  const float rstd = 1.f / sqrtf(var + 1e-5f);
  __syncthreads();

  float h0 = 0.f, h1 = 0.f, h2 = 0.f;
  for (int idx = tid; idx < kQD; idx += 256) {
    const float v = (qf[idx] - mu) * rstd * ln_g[idx] + ln_b[idx];
    qn[(size_t)n * kQD + idx] = v;
    const float pb = v * bk[idx];
    if (idx < kC) h0 += pb;
    else if (idx < 2 * kC) h1 += pb;
    else h2 += pb;
  }
#pragma unroll
  for (int off = 32; off; off >>= 1) {
    h0 += __shfl_down(h0, off);
    h1 += __shfl_down(h1, off);
    h2 += __shfl_down(h2, off);
  }
  if ((tid & 63) == 0) {
    red[(tid >> 6) * 4 + 0] = h0;
    red[(tid >> 6) * 4 + 1] = h1;
    red[(tid >> 6) * 4 + 2] = h2;
  }
  __syncthreads();
  if (tid < 3)
    qbk[n * 3 + tid] = red[tid] + red[4 + tid] + red[8 + tid] + red[12 + tid];
}

// ---- fused: project points -> bilinear-sample image feats (zeros padding)
//      -> scores -> softmax -> weighted context. One block per query pos. ----
__global__ void __launch_bounds__(256) sample_attn_kernel(
    const float* __restrict__ src, const int pixstride, const int cstride,
    const float* __restrict__ w2c, const float* __restrict__ Kin,
    const float* __restrict__ qk, const float* __restrict__ qbk,
    const int plane, float* __restrict__ wctx) {
  __shared__ float ctx[kL * kC];      // 49.3 KB
  __shared__ float su[kL], sv[kL], smk[kL];
  __shared__ float spart[4][48];
  __shared__ float ssc[48];
  __shared__ float swt[48];
  const int n = blockIdx.x, i = n >> 6, j = n & 63, tid = threadIdx.x;

  if (tid < kL) {
    const int s = tid >> 2, m = tid & 3;
    const float Xi = -1.f + 2.f * i / 63.f;
    const float Xj = -1.f + 2.f * j / 63.f;
    const float Ts = -1.f + 2.f * s / 3.f;
    float px, py, pz;
    if (plane == 0) { px = Xj; py = Xi; pz = Ts; }
    else if (plane == 1) { px = Xj; py = Ts; pz = Xi; }
    else { px = Ts; py = Xj; pz = Xi; }
    const float* W = w2c + m * 16;
    const float c0 = W[0] * px + W[1] * py + W[2] * pz + W[3];
    const float c1 = W[4] * px + W[5] * py + W[6] * pz + W[7];
    const float c2 = W[8] * px + W[9] * py + W[10] * pz + W[11];
    const float* Km = Kin + m * 9;
    const float un = Km[0] * c0 + Km[1] * c1 + Km[2] * c2;
    const float vn = Km[3] * c0 + Km[4] * c1 + Km[5] * c2;
    const float ds = c2 + 1e-8f;
    const float u = un / ds, v = vn / ds;
    const float mk =
        (c2 > 0.f && u >= 0.f && u < 64.f && v >= 0.f && v < 64.f) ? 1.f : 0.f;
    su[tid] = u; sv[tid] = v; smk[tid] = mk;
  }
  __syncthreads();

  for (int l = 0; l < kL; ++l) {
    const int m = l & 3;
    const float u = su[l], v = sv[l], mk = smk[l];
    float w00 = 0.f, w10 = 0.f, w01 = 0.f, w11 = 0.f;
    int i00 = 0, i10 = 0, i01 = 0, i11 = 0;
    if (mk != 0.f) {
      const float gx = 2.f * (u / 63.f) - 1.f;
      const float gy = 2.f * (v / 63.f) - 1.f;
      const float ix = (gx + 1.f) * 0.5f * 63.f;
      const float iy = (gy + 1.f) * 0.5f * 63.f;
      const float x0 = floorf(ix), y0 = floorf(iy);
      const float x1 = x0 + 1.f, y1 = y0 + 1.f;
      const float wx = ix - x0, wy = iy - y0;
      const float v00 = (x0 >= 0.f && x0 <= 63.f && y0 >= 0.f && y0 <= 63.f) ? 1.f : 0.f;
      const float v10 = (x1 >= 0.f && x1 <= 63.f && y0 >= 0.f && y0 <= 63.f) ? 1.f : 0.f;
      const float v01 = (x0 >= 0.f && x0 <= 63.f && y1 >= 0.f && y1 <= 63.f) ? 1.f : 0.f;
      const float v11 = (x1 >= 0.f && x1 <= 63.f && y1 >= 0.f && y1 <= 63.f) ? 1.f : 0.f;
      w00 = (1.f - wx) * (1.f - wy) * v00;
      w10 = wx * (1.f - wy) * v10;
      w01 = (1.f - wx) * wy * v01;
      w11 = wx * wy * v11;
      const int x0i = (int)fminf(fmaxf(x0, 0.f), 63.f);
      const int x1i = (int)fminf(fmaxf(x1, 0.f), 63.f);
      const int y0i = (int)fminf(fmaxf(y0, 0.f), 63.f);
      const int y1i = (int)fminf(fmaxf(y1, 0.f), 63.f);
      const int mb = m * kImgMStride;
      i00 = mb + (y0i * 64 + x0i) * pixstride;
      i10 = mb + (y0i * 64 + x1i) * pixstride;
      i01 = mb + (y1i * 64 + x0i) * pixstride;
      i11 = mb + (y1i * 64 + x1i) * pixstride;
    }
    for (int c = tid; c < kC; c += 256) {
      const int cs = c * cstride;
      ctx[l * kC + c] = src[i00 + cs] * w00 + src[i10 + cs] * w10 +
                        src[i01 + cs] * w01 + src[i11 + cs] * w11;
    }
  }
  __syncthreads();

  // scores[h,l] = sum_c ctx[l,c] * qk[n,h,c]
  float acc[48];
#pragma unroll
  for (int t = 0; t < 48; ++t) acc[t] = 0.f;
  const float* qkn = qk + (size_t)n * kQD;
  for (int c = tid; c < kC; c += 256) {
    const float q0 = qkn[c], q1 = qkn[kC + c], q2 = qkn[2 * kC + c];
#pragma unroll
    for (int l = 0; l < kL; ++l) {
      const float cv = ctx[l * kC + c];
      acc[l] = fmaf(cv, q0, acc[l]);
      acc[16 + l] = fmaf(cv, q1, acc[16 + l]);
      acc[32 + l] = fmaf(cv, q2, acc[32 + l]);
    }
  }
#pragma unroll
  for (int t = 0; t < 48; ++t) {
    float x = acc[t];
#pragma unroll
    for (int off = 32; off; off >>= 1) x += __shfl_down(x, off);
    acc[t] = x;
  }
  if ((tid & 63) == 0) {
#pragma unroll
    for (int t = 0; t < 48; ++t) spart[tid >> 6][t] = acc[t];
  }
  __syncthreads();
  if (tid < 48)
    ssc[tid] = spart[0][tid] + spart[1][tid] + spart[2][tid] + spart[3][tid] +
               qbk[n * 3 + (tid >> 4)];
  __syncthreads();
  if (tid < 3) {
    float mx = ssc[tid * 16];
#pragma unroll
    for (int l = 1; l < kL; ++l) mx = fmaxf(mx, ssc[tid * 16 + l]);
    float e[kL];
    float sum = 0.f;
#pragma unroll
    for (int l = 0; l < kL; ++l) {
      e[l] = expf(ssc[tid * 16 + l] - mx);
      sum += e[l];
    }
    const float inv = 1.f / sum;
#pragma unroll
    for (int l = 0; l < kL; ++l) swt[tid * 16 + l] = e[l] * inv;
  }
  __syncthreads();

  float* wn = wctx + (size_t)n * kQD;
  for (int c = tid; c < kC; c += 256) {
    float o0 = 0.f, o1 = 0.f, o2 = 0.f;
#pragma unroll
    for (int l = 0; l < kL; ++l) {
      const float cv = ctx[l * kC + c];
      o0 = fmaf(swt[l], cv, o0);
      o1 = fmaf(swt[16 + l], cv, o1);
      o2 = fmaf(swt[32 + l], cv, o2);
    }
    wn[c] = o0;
    wn[kC + c] = o1;
    wn[2 * kC + c] = o2;
  }
}

// ---- f32 tiled GEMM, per-head column blocks via blockIdx.z ---------------
// BT=true : C[m,j] = sum_k A[m*lda+hoff+k] * B[j*ldb+hoff+k]   (qk = qn Wk_h^T)
// BT=false: C[m,j] = sum_k A[m*lda+hoff+k] * B[k*ldb+hoff+j]   (out = wctx Wv_h)
template <bool BT, bool BIAS>
__global__ void __launch_bounds__(256) gemm_f32(
    const float* __restrict__ A, const float* __restrict__ B,
    float* __restrict__ Cp, const float* __restrict__ bias, const int M,
    const int N, const int K, const int lda, const int ldb, const int ldc,
    const int hstride) {
  constexpr int BM = 128, BN = 64, BK = 16;
  __shared__ float As[BK][BM + 4];
  __shared__ float Bs[BK][BN + 4];
  const int hoff = blockIdx.z * hstride;
  const int m0 = blockIdx.y * BM, n0 = blockIdx.x * BN;
  const int tid = threadIdx.x;
  const int ty = tid >> 4, tx = tid & 15;
  float acc[8][4];
#pragma unroll
  for (int r = 0; r < 8; ++r)
#pragma unroll
    for (int c = 0; c < 4; ++c) acc[r][c] = 0.f;

  for (int k0 = 0; k0 < K; k0 += BK) {
#pragma unroll
    for (int p = 0; p < 8; ++p) {
      const int idx = tid + p * 256;
      const int mm = idx >> 4, kk = idx & 15;
      float v = 0.f;
      if (k0 + kk < K) v = A[(size_t)(m0 + mm) * lda + hoff + k0 + kk];
      As[kk][mm] = v;
    }
    if (BT) {
#pragma unroll
      for (int p = 0; p < 4; ++p) {
        const int idx = tid + p * 256;
        const int jj = idx >> 4, kk = idx & 15;
        float v = 0.f;
        if ((n0 + jj) < N && (k0 + kk) < K)
          v = B[(size_t)(n0 + jj) * ldb + hoff + k0 + kk];
        Bs[kk][jj] = v;
      }
    } else {
#pragma unroll
      for (int p = 0; p < 4; ++p) {
        const int idx = tid + p * 256;
        const int kk = idx >> 6, jj = idx & 63;
        float v = 0.f;
        if ((n0 + jj) < N && (k0 + kk) < K)
          v = B[(size_t)(k0 + kk) * ldb + hoff + n0 + jj];
        Bs[kk][jj] = v;
      }
    }
    __syncthreads();
#pragma unroll
    for (int kk = 0; kk < BK; ++kk) {
      float a[8], b[4];
#pragma unroll
      for (int r = 0; r < 8; ++r) a[r] = As[kk][ty * 8 + r];
#pragma unroll
      for (int c = 0; c < 4; ++c) b[c] = Bs[kk][tx * 4 + c];
#pragma unroll
      for (int r = 0; r < 8; ++r)
#pragma unroll
        for (int c = 0; c < 4; ++c) acc[r][c] = fmaf(a[r], b[c], acc[r][c]);
    }
    __syncthreads();
  }
#pragma unroll
  for (int r = 0; r < 8; ++r) {
    const int mm = m0 + ty * 8 + r;
    if (mm >= M) continue;
#pragma unroll
    for (int c = 0; c < 4; ++c) {
      const int jj = n0 + tx * 4 + c;
      if (jj < N) {
        float v = acc[r][c];
        if (BIAS) v += bias[hoff + jj];
        Cp[(size_t)mm * ldc + hoff + jj] = v;
      }
    }
  }
}

// ---------------------------------------------------------------------------
extern "C" void kernel_launch(void* const* d_in, const int* in_sizes, int n_in,
                              void* d_out, int out_size, void* d_ws,
                              size_t ws_size, hipStream_t stream) {
  const float* imgf = (const float*)d_in[0];
  const float* c2w = (const float*)d_in[2];
  const float* Kin = (const float*)d_in[3];
  const float* qpl[3] = {(const float*)d_in[5], (const float*)d_in[6],
                         (const float*)d_in[7]};
  const float* Wk = (const float*)d_in[8];
  const float* bk = (const float*)d_in[9];
  const float* Wv = (const float*)d_in[10];
  const float* bv = (const float*)d_in[11];
  const float* ln_g = (const float*)d_in[12];
  const float* ln_b = (const float*)d_in[13];
  float* out = (float*)d_out;
  float* ws = (float*)d_ws;

  const size_t OFF_QBK = 64;                     // after w2c (64 floats)
  const size_t OFF_BIG = OFF_QBK + (size_t)kNPIX * 3;  // 12352
  const size_t IMGT_FLOATS = (size_t)kNV * kC * kG * kG;  // 12,632,064
  const size_t QN_FLOATS = (size_t)kNPIX * kQD;           // 9,474,048
  const bool use_tr =
      ws_size >= (OFF_BIG + IMGT_FLOATS + 2 * QN_FLOATS) * sizeof(float);

  float* w2c = ws;
  float* qbk = ws + OFF_QBK;
  float* imgt = ws + OFF_BIG;
  float* qn = use_tr ? imgt + IMGT_FLOATS : ws + OFF_BIG;  // also wctx (aliased)
  float* qkb = qn + QN_FLOATS;

  invert4_kernel<<<1, 64, 0, stream>>>(c2w, w2c);

  const float* src = imgf;
  int pixstride = 1, cstride = kG * kG;  // direct [NV,C,H,W] layout
  if (use_tr) {
    transpose_img_kernel<<<dim3(64, kNV), 256, 0, stream>>>(imgf, imgt);
    src = imgt;
    pixstride = kC;
    cstride = 1;
  }

  for (int p = 0; p < 3; ++p) {
    const float* qo0 = (p == 0) ? qpl[1] : qpl[0];
    const float* qo1 = (p == 2) ? qpl[1] : qpl[2];
    build_q_kernel<<<kNPIX, 256, 0, stream>>>(qpl[p], qo0, qo1, p, ln_g, ln_b,
                                              bk, qn, qbk);
    gemm_f32<true, false><<<dim3(13, 32, 3), 256, 0, stream>>>(
        qn, Wk, qkb, nullptr, kNPIX, kC, kC, kQD, kQD, kQD, kC);
    sample_attn_kernel<<<kNPIX, 256, 0, stream>>>(src, pixstride, cstride, w2c,
                                                  Kin, qkb, qbk, p, qn);
    gemm_f32<false, true><<<dim3(13, 32, 3), 256, 0, stream>>>(
        qn, Wv, out + (size_t)p * QN_FLOATS, bv, kNPIX, kC, kC, kQD, kQD, kQD,
        kC);
  }
}

// Round 2
// 1408.257 us; speedup vs baseline: 2.0918x; 2.0918x over previous
//
#include <hip/hip_runtime.h>
#include <math.h>

// ---------------------------------------------------------------------------
// Round 2: bf16-split MFMA GEMMs (hi/lo 3-term, ~f32 precision) replacing the
// f32 vector GEMMs. m97-style 128x128 tile, 4 waves, BK=32, global_load_lds
// width-16 with source-side XOR swizzle; 2-barrier K-loop.
// Pipeline per plane: build_q (writes bf16 splits) -> MFMA GEMM (qk, f32 out)
// -> fused sample+attn (writes wctx bf16 splits) -> MFMA GEMM (out + bias).
// Tiered workspace fallback: A(transpose+MFMA) / B(strided+MFMA) / C(f32 r1).
// ---------------------------------------------------------------------------

constexpr int kG = 64, kS = 4, kC = 771, kNV = 4;
constexpr int kQD = 2313;                  // 3 * kC
constexpr int kNPIX = 4096;                // kG * kG
constexpr int kL = 16;                     // kS * kNV
constexpr int kImgMStride = kC * kG * kG;  // per-view stride (both layouts)
constexpr int kKP = 800;                   // padded per-head K (771 -> 800)
constexpr int kLDA = 2400;                 // 3 heads * 800
constexpr int kBROWS = 896;                // padded B rows (771 -> 896)

using bf16x8 = __attribute__((ext_vector_type(8))) short;
using f32x4 = __attribute__((ext_vector_type(4))) float;

__device__ __forceinline__ unsigned short f2bf(float x) {
  unsigned int u = __float_as_uint(x);
  u = (u + 0x7FFFu + ((u >> 16) & 1u)) >> 16;
  return (unsigned short)u;
}
__device__ __forceinline__ float bf2f(unsigned short h) {
  return __uint_as_float(((unsigned int)h) << 16);
}
__device__ __forceinline__ void gload16(const unsigned short* g,
                                        unsigned short* l) {
  __builtin_amdgcn_global_load_lds(
      (const __attribute__((address_space(1))) void*)g,
      (__attribute__((address_space(3))) void*)l, 16, 0, 0);
}

// ---- tiny 4x4 batched inverse (c2w -> w2c) --------------------------------
__global__ void invert4_kernel(const float* __restrict__ c2w,
                               float* __restrict__ w2c) {
  const int m = threadIdx.x;
  if (m >= kNV) return;
  float a[4][8];
  for (int r = 0; r < 4; ++r)
    for (int c = 0; c < 4; ++c) {
      a[r][c] = c2w[m * 16 + r * 4 + c];
      a[r][4 + c] = (r == c) ? 1.f : 0.f;
    }
  for (int col = 0; col < 4; ++col) {
    int piv = col;
    float best = fabsf(a[col][col]);
    for (int r = col + 1; r < 4; ++r) {
      float t = fabsf(a[r][col]);
      if (t > best) { best = t; piv = r; }
    }
    if (piv != col)
      for (int c = 0; c < 8; ++c) {
        float t = a[col][c]; a[col][c] = a[piv][c]; a[piv][c] = t;
      }
    const float inv = 1.f / a[col][col];
    for (int c = 0; c < 8; ++c) a[col][c] *= inv;
    for (int r = 0; r < 4; ++r)
      if (r != col) {
        const float f = a[r][col];
        for (int c = 0; c < 8; ++c) a[r][c] -= f * a[col][c];
      }
  }
  for (int r = 0; r < 4; ++r)
    for (int c = 0; c < 4; ++c) w2c[m * 16 + r * 4 + c] = a[r][4 + c];
}

// ---- image feature transpose [NV,C,H,W] -> [NV,H,W,C] ---------------------
__global__ void __launch_bounds__(256) transpose_img_kernel(
    const float* __restrict__ img, float* __restrict__ out) {
  __shared__ float t[64][65];
  const int y = blockIdx.x, m = blockIdx.y, tid = threadIdx.x;
  for (int c0 = 0; c0 < kC; c0 += 64) {
    const int cw = (kC - c0) < 64 ? (kC - c0) : 64;
    for (int idx = tid; idx < cw * 64; idx += 256) {
      const int cl = idx >> 6, x = idx & 63;
      t[cl][x] = img[(((size_t)m * kC + c0 + cl) * 64 + y) * 64 + x];
    }
    __syncthreads();
    for (int idx = tid; idx < 64 * 64; idx += 256) {
      const int x = idx >> 6, cl = idx & 63;
      if (cl < cw)
        out[(((size_t)m * 64 + y) * 64 + x) * (size_t)kC + c0 + cl] = t[cl][x];
    }
    __syncthreads();
  }
}

// ---- weight prep: Wk split (no transpose), Wv transpose+split -------------
__global__ void __launch_bounds__(256) prep_wk_kernel(
    const float* __restrict__ Wk, unsigned short* __restrict__ hi,
    unsigned short* __restrict__ lo) {
  const int c = blockIdx.x, h = blockIdx.y;  // c in [0,896)
  const size_t base = ((size_t)h * kBROWS + c) * kKP;
  for (int k = threadIdx.x; k < kKP; k += 256) {
    float v = (c < kC && k < kC) ? Wk[(size_t)c * kQD + h * kC + k] : 0.f;
    const unsigned short a = f2bf(v);
    hi[base + k] = a;
    lo[base + k] = f2bf(v - bf2f(a));
  }
}

__global__ void __launch_bounds__(256) prep_wvt_kernel(
    const float* __restrict__ Wv, unsigned short* __restrict__ hi,
    unsigned short* __restrict__ lo) {
  __shared__ float t[64][65];
  const int k0 = blockIdx.x * 64, j0 = blockIdx.y * 64, h = blockIdx.z;
  const int tx = threadIdx.x & 63, ty4 = threadIdx.x >> 6;
  for (int ty = ty4; ty < 64; ty += 4) {
    const int k = k0 + ty, j = j0 + tx;
    t[ty][tx] = (k < kC && j < kC) ? Wv[(size_t)k * kQD + h * kC + j] : 0.f;
  }
  __syncthreads();
  for (int ty = ty4; ty < 64; ty += 4) {
    const int j = j0 + ty, k = k0 + tx;
    if (j < kBROWS && k < kKP) {
      const float v = t[tx][ty];
      const unsigned short a = f2bf(v);
      const size_t p = ((size_t)h * kBROWS + j) * kKP + k;
      hi[p] = a;
      lo[p] = f2bf(v - bf2f(a));
    }
  }
}

// ---- build query + layernorm; emits bf16 splits (SPLIT) or f32 (tier C) ---
template <bool SPLIT>
__global__ void __launch_bounds__(256) build_q_kernel(
    const float* __restrict__ qp, const float* __restrict__ qo0,
    const float* __restrict__ qo1, const int plane,
    const float* __restrict__ ln_g, const float* __restrict__ ln_b,
    const float* __restrict__ bk, float* __restrict__ qn,
    unsigned short* __restrict__ ahi, unsigned short* __restrict__ alo,
    float* __restrict__ qbk) {
  const int n = blockIdx.x, i = n >> 6, j = n & 63, tid = threadIdx.x;
  __shared__ float qf[kQD];
  __shared__ int sIdx[2][4][4];
  __shared__ float sW[2][4][4];
  __shared__ float red[16];

  if (tid < 8) {
    const int part = tid >> 2, s = tid & 3;
    const float Xi = -1.f + 2.f * i / 63.f;
    const float Xj = -1.f + 2.f * j / 63.f;
    const float Ts = -1.f + 2.f * s / 3.f;
    float a, b;
    if (plane == 0) { a = part ? Xi : Xj; b = Ts; }
    else if (plane == 1) {
      if (part == 0) { a = Xj; b = Ts; } else { a = Ts; b = Xi; }
    } else { a = Ts; b = part ? Xi : Xj; }
    const float ga = fminf(fmaxf((a * 0.5f + 0.5f) * 63.f, 0.f), 63.f);
    const float gb = fminf(fmaxf((b * 0.5f + 0.5f) * 63.f, 0.f), 63.f);
    const float ix = fminf(fmaxf((ga + 1.f) * 0.5f * 63.f, 0.f), 63.f);
    const float iy = fminf(fmaxf((gb + 1.f) * 0.5f * 63.f, 0.f), 63.f);
    const float x0 = floorf(ix), y0 = floorf(iy);
    const float wx = ix - x0, wy = iy - y0;
    const int x0i = (int)x0, y0i = (int)y0;
    const int x1i = (x0i + 1 > 63) ? 63 : x0i + 1;
    const int y1i = (y0i + 1 > 63) ? 63 : y0i + 1;
    sIdx[part][s][0] = (y0i * 64 + x0i) * kC;
    sIdx[part][s][1] = (y0i * 64 + x1i) * kC;
    sIdx[part][s][2] = (y1i * 64 + x0i) * kC;
    sIdx[part][s][3] = (y1i * 64 + x1i) * kC;
    sW[part][s][0] = (1.f - wx) * (1.f - wy);
    sW[part][s][1] = wx * (1.f - wy);
    sW[part][s][2] = (1.f - wx) * wy;
    sW[part][s][3] = wx * wy;
  }
  __syncthreads();

  for (int c = tid; c < kC; c += 256) {
    qf[c] = qp[(size_t)n * kC + c];
    float a1 = 0.f, a2 = 0.f;
#pragma unroll
    for (int s = 0; s < 4; ++s) {
      a1 += qo0[sIdx[0][s][0] + c] * sW[0][s][0]
          + qo0[sIdx[0][s][1] + c] * sW[0][s][1]
          + qo0[sIdx[0][s][2] + c] * sW[0][s][2]
          + qo0[sIdx[0][s][3] + c] * sW[0][s][3];
      a2 += qo1[sIdx[1][s][0] + c] * sW[1][s][0]
          + qo1[sIdx[1][s][1] + c] * sW[1][s][1]
          + qo1[sIdx[1][s][2] + c] * sW[1][s][2]
          + qo1[sIdx[1][s][3] + c] * sW[1][s][3];
    }
    qf[kC + c] = a1 * 0.25f;
    qf[2 * kC + c] = a2 * 0.25f;
  }
  __syncthreads();

  float sm = 0.f;
  for (int idx = tid; idx < kQD; idx += 256) sm += qf[idx];
#pragma unroll
  for (int off = 32; off; off >>= 1) sm += __shfl_down(sm, off);
  if ((tid & 63) == 0) red[tid >> 6] = sm;
  __syncthreads();
  const float mu = (red[0] + red[1] + red[2] + red[3]) * (1.f / kQD);
  __syncthreads();
  float sq = 0.f;
  for (int idx = tid; idx < kQD; idx += 256) {
    const float d = qf[idx] - mu;
    sq += d * d;
  }
#pragma unroll
  for (int off = 32; off; off >>= 1) sq += __shfl_down(sq, off);
  if ((tid & 63) == 0) red[tid >> 6] = sq;
  __syncthreads();
  const float var = (red[0] + red[1] + red[2] + red[3]) * (1.f / kQD);
  const float rstd = 1.f / sqrtf(var + 1e-5f);
  __syncthreads();

  float h0 = 0.f, h1 = 0.f, h2 = 0.f;
  if (SPLIT) {
    for (int idx = tid; idx < 3 * kKP; idx += 256) {
      int h, k;
      if (idx < kKP) { h = 0; k = idx; }
      else if (idx < 2 * kKP) { h = 1; k = idx - kKP; }
      else { h = 2; k = idx - 2 * kKP; }
      float v = 0.f;
      if (k < kC) {
        const int li = h * kC + k;
        v = (qf[li] - mu) * rstd * ln_g[li] + ln_b[li];
        const float pb = v * bk[li];
        if (h == 0) h0 += pb; else if (h == 1) h1 += pb; else h2 += pb;
      }
      const unsigned short hv = f2bf(v);
      ahi[(size_t)n * kLDA + idx] = hv;
      alo[(size_t)n * kLDA + idx] = f2bf(v - bf2f(hv));
    }
  } else {
    for (int idx = tid; idx < kQD; idx += 256) {
      const float v = (qf[idx] - mu) * rstd * ln_g[idx] + ln_b[idx];
      qn[(size_t)n * kQD + idx] = v;
      const float pb = v * bk[idx];
      if (idx < kC) h0 += pb;
      else if (idx < 2 * kC) h1 += pb;
      else h2 += pb;
    }
  }
#pragma unroll
  for (int off = 32; off; off >>= 1) {
    h0 += __shfl_down(h0, off);
    h1 += __shfl_down(h1, off);
    h2 += __shfl_down(h2, off);
  }
  if ((tid & 63) == 0) {
    red[(tid >> 6) * 4 + 0] = h0;
    red[(tid >> 6) * 4 + 1] = h1;
    red[(tid >> 6) * 4 + 2] = h2;
  }
  __syncthreads();
  if (tid < 3)
    qbk[n * 3 + tid] = red[tid] + red[4 + tid] + red[8 + tid] + red[12 + tid];
}

// ---- fused sample + attention; emits wctx bf16 splits (SPLIT) or f32 ------
template <bool SPLIT>
__global__ void __launch_bounds__(256) sample_attn_kernel(
    const float* __restrict__ src, const int pixstride, const int cstride,
    const float* __restrict__ w2c, const float* __restrict__ Kin,
    const float* __restrict__ qk, const float* __restrict__ qbk,
    const int plane, float* __restrict__ wctx,
    unsigned short* __restrict__ whi, unsigned short* __restrict__ wlo) {
  __shared__ float ctx[kL * kC];
  __shared__ float su[kL], sv[kL], smk[kL];
  __shared__ float spart[4][48];
  __shared__ float ssc[48];
  __shared__ float swt[48];
  const int n = blockIdx.x, i = n >> 6, j = n & 63, tid = threadIdx.x;

  if (tid < kL) {
    const int s = tid >> 2, m = tid & 3;
    const float Xi = -1.f + 2.f * i / 63.f;
    const float Xj = -1.f + 2.f * j / 63.f;
    const float Ts = -1.f + 2.f * s / 3.f;
    float px, py, pz;
    if (plane == 0) { px = Xj; py = Xi; pz = Ts; }
    else if (plane == 1) { px = Xj; py = Ts; pz = Xi; }
    else { px = Ts; py = Xj; pz = Xi; }
    const float* W = w2c + m * 16;
    const float c0 = W[0] * px + W[1] * py + W[2] * pz + W[3];
    const float c1 = W[4] * px + W[5] * py + W[6] * pz + W[7];
    const float c2 = W[8] * px + W[9] * py + W[10] * pz + W[11];
    const float* Km = Kin + m * 9;
    const float un = Km[0] * c0 + Km[1] * c1 + Km[2] * c2;
    const float vn = Km[3] * c0 + Km[4] * c1 + Km[5] * c2;
    const float ds = c2 + 1e-8f;
    const float u = un / ds, v = vn / ds;
    const float mk =
        (c2 > 0.f && u >= 0.f && u < 64.f && v >= 0.f && v < 64.f) ? 1.f : 0.f;
    su[tid] = u; sv[tid] = v; smk[tid] = mk;
  }
  __syncthreads();

  for (int l = 0; l < kL; ++l) {
    const int m = l & 3;
    const float u = su[l], v = sv[l], mk = smk[l];
    float w00 = 0.f, w10 = 0.f, w01 = 0.f, w11 = 0.f;
    int i00 = 0, i10 = 0, i01 = 0, i11 = 0;
    if (mk != 0.f) {
      const float gx = 2.f * (u / 63.f) - 1.f;
      const float gy = 2.f * (v / 63.f) - 1.f;
      const float ix = (gx + 1.f) * 0.5f * 63.f;
      const float iy = (gy + 1.f) * 0.5f * 63.f;
      const float x0 = floorf(ix), y0 = floorf(iy);
      const float x1 = x0 + 1.f, y1 = y0 + 1.f;
      const float wx = ix - x0, wy = iy - y0;
      const float v00 = (x0 >= 0.f && x0 <= 63.f && y0 >= 0.f && y0 <= 63.f) ? 1.f : 0.f;
      const float v10 = (x1 >= 0.f && x1 <= 63.f && y0 >= 0.f && y0 <= 63.f) ? 1.f : 0.f;
      const float v01 = (x0 >= 0.f && x0 <= 63.f && y1 >= 0.f && y1 <= 63.f) ? 1.f : 0.f;
      const float v11 = (x1 >= 0.f && x1 <= 63.f && y1 >= 0.f && y1 <= 63.f) ? 1.f : 0.f;
      w00 = (1.f - wx) * (1.f - wy) * v00;
      w10 = wx * (1.f - wy) * v10;
      w01 = (1.f - wx) * wy * v01;
      w11 = wx * wy * v11;
      const int x0i = (int)fminf(fmaxf(x0, 0.f), 63.f);
      const int x1i = (int)fminf(fmaxf(x1, 0.f), 63.f);
      const int y0i = (int)fminf(fmaxf(y0, 0.f), 63.f);
      const int y1i = (int)fminf(fmaxf(y1, 0.f), 63.f);
      const int mb = m * kImgMStride;
      i00 = mb + (y0i * 64 + x0i) * pixstride;
      i10 = mb + (y0i * 64 + x1i) * pixstride;
      i01 = mb + (y1i * 64 + x0i) * pixstride;
      i11 = mb + (y1i * 64 + x1i) * pixstride;
    }
    for (int c = tid; c < kC; c += 256) {
      const int cs = c * cstride;
      ctx[l * kC + c] = src[i00 + cs] * w00 + src[i10 + cs] * w10 +
                        src[i01 + cs] * w01 + src[i11 + cs] * w11;
    }
  }
  __syncthreads();

  float acc[48];
#pragma unroll
  for (int t = 0; t < 48; ++t) acc[t] = 0.f;
  const float* qkn = qk + (size_t)n * kQD;
  for (int c = tid; c < kC; c += 256) {
    const float q0 = qkn[c], q1 = qkn[kC + c], q2 = qkn[2 * kC + c];
#pragma unroll
    for (int l = 0; l < kL; ++l) {
      const float cv = ctx[l * kC + c];
      acc[l] = fmaf(cv, q0, acc[l]);
      acc[16 + l] = fmaf(cv, q1, acc[16 + l]);
      acc[32 + l] = fmaf(cv, q2, acc[32 + l]);
    }
  }
#pragma unroll
  for (int t = 0; t < 48; ++t) {
    float x = acc[t];
#pragma unroll
    for (int off = 32; off; off >>= 1) x += __shfl_down(x, off);
    acc[t] = x;
  }
  if ((tid & 63) == 0) {
#pragma unroll
    for (int t = 0; t < 48; ++t) spart[tid >> 6][t] = acc[t];
  }
  __syncthreads();
  if (tid < 48)
    ssc[tid] = spart[0][tid] + spart[1][tid] + spart[2][tid] + spart[3][tid] +
               qbk[n * 3 + (tid >> 4)];
  __syncthreads();
  if (tid < 3) {
    float mx = ssc[tid * 16];
#pragma unroll
    for (int l = 1; l < kL; ++l) mx = fmaxf(mx, ssc[tid * 16 + l]);
    float e[kL];
    float sum = 0.f;
#pragma unroll
    for (int l = 0; l < kL; ++l) {
      e[l] = expf(ssc[tid * 16 + l] - mx);
      sum += e[l];
    }
    const float inv = 1.f / sum;
#pragma unroll
    for (int l = 0; l < kL; ++l) swt[tid * 16 + l] = e[l] * inv;
  }
  __syncthreads();

  for (int c = tid; c < kC; c += 256) {
    float o0 = 0.f, o1 = 0.f, o2 = 0.f;
#pragma unroll
    for (int l = 0; l < kL; ++l) {
      const float cv = ctx[l * kC + c];
      o0 = fmaf(swt[l], cv, o0);
      o1 = fmaf(swt[16 + l], cv, o1);
      o2 = fmaf(swt[32 + l], cv, o2);
    }
    if (SPLIT) {
      const size_t base = (size_t)n * kLDA;
      unsigned short t0 = f2bf(o0), t1 = f2bf(o1), t2 = f2bf(o2);
      whi[base + c] = t0;
      whi[base + kKP + c] = t1;
      whi[base + 2 * kKP + c] = t2;
      wlo[base + c] = f2bf(o0 - bf2f(t0));
      wlo[base + kKP + c] = f2bf(o1 - bf2f(t1));
      wlo[base + 2 * kKP + c] = f2bf(o2 - bf2f(t2));
    } else {
      float* wn = wctx + (size_t)n * kQD;
      wn[c] = o0;
      wn[kC + c] = o1;
      wn[2 * kC + c] = o2;
    }
  }
  if (SPLIT && tid < 3 * (kKP - kC)) {  // zero the 29-wide K pad per head
    const int h = tid / (kKP - kC), k = kC + tid % (kKP - kC);
    const size_t p = (size_t)n * kLDA + h * kKP + k;
    whi[p] = 0; wlo[p] = 0;
  }
}

// ---- bf16-split MFMA GEMM: C[m, h*771+j] = sum_k A[m,h*800+k]*B[h][j][k] ---
// A: [4096][2400] bf16 splits; B: [3][896][800] bf16 splits (K-contiguous).
// 128x128 tile, 4 waves (2x2 of 64x64), BK=32, 48 MFMA/K-step (3-term split).
template <bool BIAS>
__global__ void __launch_bounds__(256) gemm_mfma(
    const unsigned short* __restrict__ Ahi, const unsigned short* __restrict__ Alo,
    const unsigned short* __restrict__ Bhi, const unsigned short* __restrict__ Blo,
    float* __restrict__ C, const float* __restrict__ bias) {
  constexpr int LDC = kQD;
  __shared__ unsigned short smA[2][128 * 32];  // hi, lo
  __shared__ unsigned short smB[2][128 * 32];
  const int h = blockIdx.z;
  const int m0 = blockIdx.y * 128;
  const int n0 = blockIdx.x * 128;
  const int tid = threadIdx.x;
  const int lane = tid & 63, w = tid >> 6;
  const int wm = w >> 1, wn = w & 1;

  // staging: thread covers row r = p*64 + w*16 + (lane>>2), phys slot lane&3
  const int sr0 = w * 16 + (lane >> 2);
  const int ss = lane & 3;
  size_t aoff[2], boff[2];
  int ldsb[2];
#pragma unroll
  for (int p = 0; p < 2; ++p) {
    const int r = p * 64 + sr0;
    const int kl = (ss ^ ((r >> 1) & 3)) * 8;  // logical k16 slot for this phys
    aoff[p] = (size_t)(m0 + r) * kLDA + (size_t)h * kKP + kl;
    boff[p] = ((size_t)h * kBROWS + (n0 + r)) * kKP + kl;
    ldsb[p] = (p * 64 + w * 16) * 32;
  }

  // fragment LDS offsets (elements), constant across K-loop
  int offA[4], offB[4];
#pragma unroll
  for (int i = 0; i < 4; ++i) {
    const int ra = wm * 64 + i * 16 + (lane & 15);
    offA[i] = ra * 32 + (((lane >> 4) ^ ((ra >> 1) & 3)) << 3);
    const int rb = wn * 64 + i * 16 + (lane & 15);
    offB[i] = rb * 32 + (((lane >> 4) ^ ((rb >> 1) & 3)) << 3);
  }

  f32x4 acc[4][4];
#pragma unroll
  for (int i = 0; i < 4; ++i)
#pragma unroll
    for (int j = 0; j < 4; ++j) acc[i][j] = f32x4{0.f, 0.f, 0.f, 0.f};

  for (int k0 = 0; k0 < kKP; k0 += 32) {
#pragma unroll
    for (int p = 0; p < 2; ++p) {
      gload16(Ahi + aoff[p] + k0, &smA[0][ldsb[p]]);
      gload16(Alo + aoff[p] + k0, &smA[1][ldsb[p]]);
      gload16(Bhi + boff[p] + k0, &smB[0][ldsb[p]]);
      gload16(Blo + boff[p] + k0, &smB[1][ldsb[p]]);
    }
    __syncthreads();
    bf16x8 ah[4], al[4], bh[4], bl[4];
#pragma unroll
    for (int i = 0; i < 4; ++i) {
      ah[i] = *(const bf16x8*)&smA[0][offA[i]];
      al[i] = *(const bf16x8*)&smA[1][offA[i]];
      bh[i] = *(const bf16x8*)&smB[0][offB[i]];
      bl[i] = *(const bf16x8*)&smB[1][offB[i]];
    }
#pragma unroll
    for (int i = 0; i < 4; ++i)
#pragma unroll
      for (int j = 0; j < 4; ++j)
        acc[i][j] =
            __builtin_amdgcn_mfma_f32_16x16x32_bf16(ah[i], bh[j], acc[i][j], 0, 0, 0);
#pragma unroll
    for (int i = 0; i < 4; ++i)
#pragma unroll
      for (int j = 0; j < 4; ++j)
        acc[i][j] =
            __builtin_amdgcn_mfma_f32_16x16x32_bf16(ah[i], bl[j], acc[i][j], 0, 0, 0);
#pragma unroll
    for (int i = 0; i < 4; ++i)
#pragma unroll
      for (int j = 0; j < 4; ++j)
        acc[i][j] =
            __builtin_amdgcn_mfma_f32_16x16x32_bf16(al[i], bh[j], acc[i][j], 0, 0, 0);
    __syncthreads();
  }

  const int rbase = m0 + wm * 64;
  const int cbase = n0 + wn * 64;
#pragma unroll
  for (int i = 0; i < 4; ++i) {
#pragma unroll
    for (int j = 0; j < 4; ++j) {
      const int col = cbase + j * 16 + (lane & 15);
      if (col < kC) {
        const float bb = BIAS ? bias[h * kC + col] : 0.f;
#pragma unroll
        for (int r = 0; r < 4; ++r) {
          const int row = rbase + i * 16 + (lane >> 4) * 4 + r;
          C[(size_t)row * LDC + h * kC + col] = acc[i][j][r] + bb;
        }
      }
    }
  }
}

// ---- tier-C fallback f32 GEMM (round 1) -----------------------------------
template <bool BT, bool BIAS>
__global__ void __launch_bounds__(256) gemm_f32(
    const float* __restrict__ A, const float* __restrict__ B,
    float* __restrict__ Cp, const float* __restrict__ bias, const int M,
    const int N, const int K, const int lda, const int ldb, const int ldc,
    const int hstride) {
  constexpr int BM = 128, BN = 64, BK = 16;
  __shared__ float As[BK][BM + 4];
  __shared__ float Bs[BK][BN + 4];
  const int hoff = blockIdx.z * hstride;
  const int m0 = blockIdx.y * BM, n0 = blockIdx.x * BN;
  const int tid = threadIdx.x;
  const int ty = tid >> 4, tx = tid & 15;
  float acc[8][4];
#pragma unroll
  for (int r = 0; r < 8; ++r)
#pragma unroll
    for (int c = 0; c < 4; ++c) acc[r][c] = 0.f;
  for (int k0 = 0; k0 < K; k0 += BK) {
#pragma unroll
    for (int p = 0; p < 8; ++p) {
      const int idx = tid + p * 256;
      const int mm = idx >> 4, kk = idx & 15;
      float v = 0.f;
      if (k0 + kk < K) v = A[(size_t)(m0 + mm) * lda + hoff + k0 + kk];
      As[kk][mm] = v;
    }
    if (BT) {
#pragma unroll
      for (int p = 0; p < 4; ++p) {
        const int idx = tid + p * 256;
        const int jj = idx >> 4, kk = idx & 15;
        float v = 0.f;
        if ((n0 + jj) < N && (k0 + kk) < K)
          v = B[(size_t)(n0 + jj) * ldb + hoff + k0 + kk];
        Bs[kk][jj] = v;
      }
    } else {
#pragma unroll
      for (int p = 0; p < 4; ++p) {
        const int idx = tid + p * 256;
        const int kk = idx >> 6, jj = idx & 63;
        float v = 0.f;
        if ((n0 + jj) < N && (k0 + kk) < K)
          v = B[(size_t)(k0 + kk) * ldb + hoff + n0 + jj];
        Bs[kk][jj] = v;
      }
    }
    __syncthreads();
#pragma unroll
    for (int kk = 0; kk < BK; ++kk) {
      float a[8], b[4];
#pragma unroll
      for (int r = 0; r < 8; ++r) a[r] = As[kk][ty * 8 + r];
#pragma unroll
      for (int c = 0; c < 4; ++c) b[c] = Bs[kk][tx * 4 + c];
#pragma unroll
      for (int r = 0; r < 8; ++r)
#pragma unroll
        for (int c = 0; c < 4; ++c) acc[r][c] = fmaf(a[r], b[c], acc[r][c]);
    }
    __syncthreads();
  }
#pragma unroll
  for (int r = 0; r < 8; ++r) {
    const int mm = m0 + ty * 8 + r;
    if (mm >= M) continue;
#pragma unroll
    for (int c = 0; c < 4; ++c) {
      const int jj = n0 + tx * 4 + c;
      if (jj < N) {
        float v = acc[r][c];
        if (BIAS) v += bias[hoff + jj];
        Cp[(size_t)mm * ldc + hoff + jj] = v;
      }
    }
  }
}

// ---------------------------------------------------------------------------
extern "C" void kernel_launch(void* const* d_in, const int* in_sizes, int n_in,
                              void* d_out, int out_size, void* d_ws,
                              size_t ws_size, hipStream_t stream) {
  const float* imgf = (const float*)d_in[0];
  const float* c2w = (const float*)d_in[2];
  const float* Kin = (const float*)d_in[3];
  const float* qpl[3] = {(const float*)d_in[5], (const float*)d_in[6],
                         (const float*)d_in[7]};
  const float* Wk = (const float*)d_in[8];
  const float* bk = (const float*)d_in[9];
  const float* Wv = (const float*)d_in[10];
  const float* bv = (const float*)d_in[11];
  const float* ln_g = (const float*)d_in[12];
  const float* ln_b = (const float*)d_in[13];
  float* out = (float*)d_out;
  char* wsb = (char*)d_ws;

  const size_t QN_FLOATS = (size_t)kNPIX * kQD;           // 9,474,048
  const size_t IMGT_FLOATS = (size_t)kNV * kC * kG * kG;  // 12,632,064
  const size_t W_ELEMS = (size_t)3 * kBROWS * kKP;        // 2,150,400
  const size_t A_ELEMS = (size_t)kNPIX * kLDA;            // 9,830,400

  size_t off = 0;
  auto take = [&](size_t bytes) {
    size_t o = off;
    off = (off + bytes + 511) & ~(size_t)511;
    return o;
  };
  const size_t o_w2c = take(64 * 4);
  const size_t o_qbk = take((size_t)kNPIX * 3 * 4);
  const size_t o_qkb = take(QN_FLOATS * 4);
  const size_t o_wkhi = take(W_ELEMS * 2);
  const size_t o_wklo = take(W_ELEMS * 2);
  const size_t o_wvthi = take(W_ELEMS * 2);
  const size_t o_wvtlo = take(W_ELEMS * 2);
  const size_t o_ahi = take(A_ELEMS * 2);
  const size_t o_alo = take(A_ELEMS * 2);
  const size_t need_B = off;
  const size_t o_imgt = take(IMGT_FLOATS * 4);
  const size_t need_A = off;

  const int tier = (ws_size >= need_A) ? 0 : (ws_size >= need_B) ? 1 : 2;

  if (tier <= 1) {
    float* w2c = (float*)(wsb + o_w2c);
    float* qbk = (float*)(wsb + o_qbk);
    float* qkb = (float*)(wsb + o_qkb);
    unsigned short* wkhi = (unsigned short*)(wsb + o_wkhi);
    unsigned short* wklo = (unsigned short*)(wsb + o_wklo);
    unsigned short* wvthi = (unsigned short*)(wsb + o_wvthi);
    unsigned short* wvtlo = (unsigned short*)(wsb + o_wvtlo);
    unsigned short* ahi = (unsigned short*)(wsb + o_ahi);
    unsigned short* alo = (unsigned short*)(wsb + o_alo);
    float* imgt = (float*)(wsb + o_imgt);

    invert4_kernel<<<1, 64, 0, stream>>>(c2w, w2c);
    prep_wk_kernel<<<dim3(kBROWS, 3), 256, 0, stream>>>(Wk, wkhi, wklo);
    prep_wvt_kernel<<<dim3(13, 14, 3), 256, 0, stream>>>(Wv, wvthi, wvtlo);

    const float* src = imgf;
    int pixstride = 1, cstride = kG * kG;
    if (tier == 0) {
      transpose_img_kernel<<<dim3(64, kNV), 256, 0, stream>>>(imgf, imgt);
      src = imgt;
      pixstride = kC;
      cstride = 1;
    }

    for (int p = 0; p < 3; ++p) {
      const float* qo0 = (p == 0) ? qpl[1] : qpl[0];
      const float* qo1 = (p == 2) ? qpl[1] : qpl[2];
      build_q_kernel<true><<<kNPIX, 256, 0, stream>>>(
          qpl[p], qo0, qo1, p, ln_g, ln_b, bk, nullptr, ahi, alo, qbk);
      gemm_mfma<false><<<dim3(7, 32, 3), 256, 0, stream>>>(ahi, alo, wkhi,
                                                           wklo, qkb, nullptr);
      sample_attn_kernel<true><<<kNPIX, 256, 0, stream>>>(
          src, pixstride, cstride, w2c, Kin, qkb, qbk, p, nullptr, ahi, alo);
      gemm_mfma<true><<<dim3(7, 32, 3), 256, 0, stream>>>(
          ahi, alo, wvthi, wvtlo, out + (size_t)p * QN_FLOATS, bv);
    }
  } else {
    // tier C: round-1 f32 path (known-good footprint)
    float* ws = (float*)d_ws;
    const size_t OFF_QBK = 64;
    const size_t OFF_BIG = OFF_QBK + (size_t)kNPIX * 3;
    float* w2c = ws;
    float* qbk = ws + OFF_QBK;
    float* qn = ws + OFF_BIG;
    float* qkb = qn + QN_FLOATS;

    invert4_kernel<<<1, 64, 0, stream>>>(c2w, w2c);
    for (int p = 0; p < 3; ++p) {
      const float* qo0 = (p == 0) ? qpl[1] : qpl[0];
      const float* qo1 = (p == 2) ? qpl[1] : qpl[2];
      build_q_kernel<false><<<kNPIX, 256, 0, stream>>>(
          qpl[p], qo0, qo1, p, ln_g, ln_b, bk, qn, nullptr, nullptr, qbk);
      gemm_f32<true, false><<<dim3(13, 32, 3), 256, 0, stream>>>(
          qn, Wk, qkb, nullptr, kNPIX, kC, kC, kQD, kQD, kQD, kC);
      sample_attn_kernel<false><<<kNPIX, 256, 0, stream>>>(
          imgf, 1, kG * kG, w2c, Kin, qkb, qbk, p, qn, nullptr, nullptr);
      gemm_f32<false, true><<<dim3(13, 32, 3), 256, 0, stream>>>(
          qn, Wv, out + (size_t)p * QN_FLOATS, bv, kNPIX, kC, kC, kQD, kQD,
          kQD, kC);
    }
  }
}

// Round 3
// 1067.609 us; speedup vs baseline: 2.7592x; 1.3191x over previous
//
#include <hip/hip_runtime.h>
#include <math.h>

// ---------------------------------------------------------------------------
// Round 3: sample_attn rewritten — float4 staging (imgt padded to 776 ch),
// group-of-16 scores (width-16 shuffle reduce), float4 PV with ushort4 split
// stores, XCD swizzle. qkb rows padded to 3x776 (16B aligned, zero-filled
// pad) so scores can vector-load qk. GEMMs unchanged (bf16-split MFMA).
// ---------------------------------------------------------------------------

constexpr int kG = 64, kS = 4, kC = 771, kNV = 4;
constexpr int kQD = 2313;                  // 3 * kC
constexpr int kNPIX = 4096;                // kG * kG
constexpr int kL = 16;                     // kS * kNV
constexpr int kImgMStride = kC * kG * kG;  // view stride, original layout
constexpr int kKP = 800;                   // padded per-head K (771 -> 800)
constexpr int kLDA = 2400;                 // 3 heads * 800
constexpr int kBROWS = 896;                // padded B rows (771 -> 896)
constexpr int kCP = 776;                   // padded channels (float4)
constexpr int kNG = kCP / 4;               // 194 float4 groups
constexpr int kLDQ = 3 * kCP;              // 2328 qkb row stride
constexpr int kIMS2 = kNPIX * kCP;         // padded view stride

using bf16x8 = __attribute__((ext_vector_type(8))) short;
using f32x4 = __attribute__((ext_vector_type(4))) float;

__device__ __forceinline__ unsigned short f2bf(float x) {
  unsigned int u = __float_as_uint(x);
  u = (u + 0x7FFFu + ((u >> 16) & 1u)) >> 16;
  return (unsigned short)u;
}
__device__ __forceinline__ float bf2f(unsigned short h) {
  return __uint_as_float(((unsigned int)h) << 16);
}
__device__ __forceinline__ void gload16(const unsigned short* g,
                                        unsigned short* l) {
  __builtin_amdgcn_global_load_lds(
      (const __attribute__((address_space(1))) void*)g,
      (__attribute__((address_space(3))) void*)l, 16, 0, 0);
}

// ---- tiny 4x4 batched inverse (c2w -> w2c) --------------------------------
__global__ void invert4_kernel(const float* __restrict__ c2w,
                               float* __restrict__ w2c) {
  const int m = threadIdx.x;
  if (m >= kNV) return;
  float a[4][8];
  for (int r = 0; r < 4; ++r)
    for (int c = 0; c < 4; ++c) {
      a[r][c] = c2w[m * 16 + r * 4 + c];
      a[r][4 + c] = (r == c) ? 1.f : 0.f;
    }
  for (int col = 0; col < 4; ++col) {
    int piv = col;
    float best = fabsf(a[col][col]);
    for (int r = col + 1; r < 4; ++r) {
      float t = fabsf(a[r][col]);
      if (t > best) { best = t; piv = r; }
    }
    if (piv != col)
      for (int c = 0; c < 8; ++c) {
        float t = a[col][c]; a[col][c] = a[piv][c]; a[piv][c] = t;
      }
    const float inv = 1.f / a[col][col];
    for (int c = 0; c < 8; ++c) a[col][c] *= inv;
    for (int r = 0; r < 4; ++r)
      if (r != col) {
        const float f = a[r][col];
        for (int c = 0; c < 8; ++c) a[r][c] -= f * a[col][c];
      }
  }
  for (int r = 0; r < 4; ++r)
    for (int c = 0; c < 4; ++c) w2c[m * 16 + r * 4 + c] = a[r][4 + c];
}

// ---- image transpose [NV,C,H,W] -> [NV,H,W,776] (zero pad 771..775) ------
__global__ void __launch_bounds__(256) transpose_img_kernel(
    const float* __restrict__ img, float* __restrict__ out) {
  __shared__ float t[64][65];
  const int y = blockIdx.x, m = blockIdx.y, tid = threadIdx.x;
  const size_t obase = ((size_t)m * kNPIX + (size_t)y * 64) * kCP;
  for (int c0 = 0; c0 < kC; c0 += 64) {
    const int cw = (kC - c0) < 64 ? (kC - c0) : 64;
    for (int idx = tid; idx < cw * 64; idx += 256) {
      const int cl = idx >> 6, x = idx & 63;
      t[cl][x] = img[(((size_t)m * kC + c0 + cl) * 64 + y) * 64 + x];
    }
    __syncthreads();
    for (int idx = tid; idx < 64 * 64; idx += 256) {
      const int x = idx >> 6, cl = idx & 63;
      if (cl < cw) out[obase + (size_t)x * kCP + c0 + cl] = t[cl][x];
    }
    __syncthreads();
  }
  for (int idx = tid; idx < 64 * 8; idx += 256) {
    const int x = idx >> 3, c = 768 + (idx & 7);
    if (c >= kC && c < kCP) out[obase + (size_t)x * kCP + c] = 0.f;
  }
}

// ---- weight prep: Wk split (no transpose), Wv transpose+split -------------
__global__ void __launch_bounds__(256) prep_wk_kernel(
    const float* __restrict__ Wk, unsigned short* __restrict__ hi,
    unsigned short* __restrict__ lo) {
  const int c = blockIdx.x, h = blockIdx.y;  // c in [0,896)
  const size_t base = ((size_t)h * kBROWS + c) * kKP;
  for (int k = threadIdx.x; k < kKP; k += 256) {
    float v = (c < kC && k < kC) ? Wk[(size_t)c * kQD + h * kC + k] : 0.f;
    const unsigned short a = f2bf(v);
    hi[base + k] = a;
    lo[base + k] = f2bf(v - bf2f(a));
  }
}

__global__ void __launch_bounds__(256) prep_wvt_kernel(
    const float* __restrict__ Wv, unsigned short* __restrict__ hi,
    unsigned short* __restrict__ lo) {
  __shared__ float t[64][65];
  const int k0 = blockIdx.x * 64, j0 = blockIdx.y * 64, h = blockIdx.z;
  const int tx = threadIdx.x & 63, ty4 = threadIdx.x >> 6;
  for (int ty = ty4; ty < 64; ty += 4) {
    const int k = k0 + ty, j = j0 + tx;
    t[ty][tx] = (k < kC && j < kC) ? Wv[(size_t)k * kQD + h * kC + j] : 0.f;
  }
  __syncthreads();
  for (int ty = ty4; ty < 64; ty += 4) {
    const int j = j0 + ty, k = k0 + tx;
    if (j < kBROWS && k < kKP) {
      const float v = t[tx][ty];
      const unsigned short a = f2bf(v);
      const size_t p = ((size_t)h * kBROWS + j) * kKP + k;
      hi[p] = a;
      lo[p] = f2bf(v - bf2f(a));
    }
  }
}

// ---- build query + layernorm; emits bf16 splits (SPLIT) or f32 (tier C) ---
template <bool SPLIT>
__global__ void __launch_bounds__(256) build_q_kernel(
    const float* __restrict__ qp, const float* __restrict__ qo0,
    const float* __restrict__ qo1, const int plane,
    const float* __restrict__ ln_g, const float* __restrict__ ln_b,
    const float* __restrict__ bk, float* __restrict__ qn,
    unsigned short* __restrict__ ahi, unsigned short* __restrict__ alo,
    float* __restrict__ qbk) {
  const int n = blockIdx.x, i = n >> 6, j = n & 63, tid = threadIdx.x;
  __shared__ float qf[kQD];
  __shared__ int sIdx[2][4][4];
  __shared__ float sW[2][4][4];
  __shared__ float red[16];

  if (tid < 8) {
    const int part = tid >> 2, s = tid & 3;
    const float Xi = -1.f + 2.f * i / 63.f;
    const float Xj = -1.f + 2.f * j / 63.f;
    const float Ts = -1.f + 2.f * s / 3.f;
    float a, b;
    if (plane == 0) { a = part ? Xi : Xj; b = Ts; }
    else if (plane == 1) {
      if (part == 0) { a = Xj; b = Ts; } else { a = Ts; b = Xi; }
    } else { a = Ts; b = part ? Xi : Xj; }
    const float ga = fminf(fmaxf((a * 0.5f + 0.5f) * 63.f, 0.f), 63.f);
    const float gb = fminf(fmaxf((b * 0.5f + 0.5f) * 63.f, 0.f), 63.f);
    const float ix = fminf(fmaxf((ga + 1.f) * 0.5f * 63.f, 0.f), 63.f);
    const float iy = fminf(fmaxf((gb + 1.f) * 0.5f * 63.f, 0.f), 63.f);
    const float x0 = floorf(ix), y0 = floorf(iy);
    const float wx = ix - x0, wy = iy - y0;
    const int x0i = (int)x0, y0i = (int)y0;
    const int x1i = (x0i + 1 > 63) ? 63 : x0i + 1;
    const int y1i = (y0i + 1 > 63) ? 63 : y0i + 1;
    sIdx[part][s][0] = (y0i * 64 + x0i) * kC;
    sIdx[part][s][1] = (y0i * 64 + x1i) * kC;
    sIdx[part][s][2] = (y1i * 64 + x0i) * kC;
    sIdx[part][s][3] = (y1i * 64 + x1i) * kC;
    sW[part][s][0] = (1.f - wx) * (1.f - wy);
    sW[part][s][1] = wx * (1.f - wy);
    sW[part][s][2] = (1.f - wx) * wy;
    sW[part][s][3] = wx * wy;
  }
  __syncthreads();

  for (int c = tid; c < kC; c += 256) {
    qf[c] = qp[(size_t)n * kC + c];
    float a1 = 0.f, a2 = 0.f;
#pragma unroll
    for (int s = 0; s < 4; ++s) {
      a1 += qo0[sIdx[0][s][0] + c] * sW[0][s][0]
          + qo0[sIdx[0][s][1] + c] * sW[0][s][1]
          + qo0[sIdx[0][s][2] + c] * sW[0][s][2]
          + qo0[sIdx[0][s][3] + c] * sW[0][s][3];
      a2 += qo1[sIdx[1][s][0] + c] * sW[1][s][0]
          + qo1[sIdx[1][s][1] + c] * sW[1][s][1]
          + qo1[sIdx[1][s][2] + c] * sW[1][s][2]
          + qo1[sIdx[1][s][3] + c] * sW[1][s][3];
    }
    qf[kC + c] = a1 * 0.25f;
    qf[2 * kC + c] = a2 * 0.25f;
  }
  __syncthreads();

  float sm = 0.f;
  for (int idx = tid; idx < kQD; idx += 256) sm += qf[idx];
#pragma unroll
  for (int off = 32; off; off >>= 1) sm += __shfl_down(sm, off);
  if ((tid & 63) == 0) red[tid >> 6] = sm;
  __syncthreads();
  const float mu = (red[0] + red[1] + red[2] + red[3]) * (1.f / kQD);
  __syncthreads();
  float sq = 0.f;
  for (int idx = tid; idx < kQD; idx += 256) {
    const float d = qf[idx] - mu;
    sq += d * d;
  }
#pragma unroll
  for (int off = 32; off; off >>= 1) sq += __shfl_down(sq, off);
  if ((tid & 63) == 0) red[tid >> 6] = sq;
  __syncthreads();
  const float var = (red[0] + red[1] + red[2] + red[3]) * (1.f / kQD);
  const float rstd = 1.f / sqrtf(var + 1e-5f);
  __syncthreads();

  float h0 = 0.f, h1 = 0.f, h2 = 0.f;
  if (SPLIT) {
    for (int idx = tid; idx < 3 * kKP; idx += 256) {
      int h, k;
      if (idx < kKP) { h = 0; k = idx; }
      else if (idx < 2 * kKP) { h = 1; k = idx - kKP; }
      else { h = 2; k = idx - 2 * kKP; }
      float v = 0.f;
      if (k < kC) {
        const int li = h * kC + k;
        v = (qf[li] - mu) * rstd * ln_g[li] + ln_b[li];
        const float pb = v * bk[li];
        if (h == 0) h0 += pb; else if (h == 1) h1 += pb; else h2 += pb;
      }
      const unsigned short hv = f2bf(v);
      ahi[(size_t)n * kLDA + idx] = hv;
      alo[(size_t)n * kLDA + idx] = f2bf(v - bf2f(hv));
    }
  } else {
    for (int idx = tid; idx < kQD; idx += 256) {
      const float v = (qf[idx] - mu) * rstd * ln_g[idx] + ln_b[idx];
      qn[(size_t)n * kQD + idx] = v;
      const float pb = v * bk[idx];
      if (idx < kC) h0 += pb;
      else if (idx < 2 * kC) h1 += pb;
      else h2 += pb;
    }
  }
#pragma unroll
  for (int off = 32; off; off >>= 1) {
    h0 += __shfl_down(h0, off);
    h1 += __shfl_down(h1, off);
    h2 += __shfl_down(h2, off);
  }
  if ((tid & 63) == 0) {
    red[(tid >> 6) * 4 + 0] = h0;
    red[(tid >> 6) * 4 + 1] = h1;
    red[(tid >> 6) * 4 + 2] = h2;
  }
  __syncthreads();
  if (tid < 3)
    qbk[n * 3 + tid] = red[tid] + red[4 + tid] + red[8 + tid] + red[12 + tid];
}

// ---- NEW fused sample+attn: float4 staging, group-16 scores, float4 PV ----
__global__ void __launch_bounds__(256) sample_attn2_kernel(
    const float* __restrict__ imgt, const float* __restrict__ w2c,
    const float* __restrict__ Kin, const float* __restrict__ qk,
    const float* __restrict__ qbk, const int plane,
    unsigned short* __restrict__ whi, unsigned short* __restrict__ wlo) {
  __shared__ __align__(16) float ctx[kL][kCP];  // 49.7 KB
  __shared__ float sW2[kL][4];
  __shared__ int sI2[kL][4];
  __shared__ float ssc[48], swt[48];
  const int bid = blockIdx.x;
  const int n = ((bid & 7) << 9) | (bid >> 3);  // XCD swizzle (bijective)
  const int i = n >> 6, j = n & 63, tid = threadIdx.x;

  if (tid < kL) {
    const int s = tid >> 2, m = tid & 3;
    const float Xi = -1.f + 2.f * i / 63.f;
    const float Xj = -1.f + 2.f * j / 63.f;
    const float Ts = -1.f + 2.f * s / 3.f;
    float px, py, pz;
    if (plane == 0) { px = Xj; py = Xi; pz = Ts; }
    else if (plane == 1) { px = Xj; py = Ts; pz = Xi; }
    else { px = Ts; py = Xj; pz = Xi; }
    const float* W = w2c + m * 16;
    const float c0 = W[0] * px + W[1] * py + W[2] * pz + W[3];
    const float c1 = W[4] * px + W[5] * py + W[6] * pz + W[7];
    const float c2 = W[8] * px + W[9] * py + W[10] * pz + W[11];
    const float* Km = Kin + m * 9;
    const float un = Km[0] * c0 + Km[1] * c1 + Km[2] * c2;
    const float vn = Km[3] * c0 + Km[4] * c1 + Km[5] * c2;
    const float ds = c2 + 1e-8f;
    const float u = un / ds, v = vn / ds;
    const bool mk =
        (c2 > 0.f && u >= 0.f && u < 64.f && v >= 0.f && v < 64.f);
    float w00 = 0.f, w10 = 0.f, w01 = 0.f, w11 = 0.f;
    int i00 = 0, i10 = 0, i01 = 0, i11 = 0;
    if (mk) {
      const float gx = 2.f * (u / 63.f) - 1.f;
      const float gy = 2.f * (v / 63.f) - 1.f;
      const float ix = (gx + 1.f) * 0.5f * 63.f;
      const float iy = (gy + 1.f) * 0.5f * 63.f;
      const float x0 = floorf(ix), y0 = floorf(iy);
      const float x1 = x0 + 1.f, y1 = y0 + 1.f;
      const float wx = ix - x0, wy = iy - y0;
      const float v00 = (x0 >= 0.f && x0 <= 63.f && y0 >= 0.f && y0 <= 63.f) ? 1.f : 0.f;
      const float v10 = (x1 >= 0.f && x1 <= 63.f && y0 >= 0.f && y0 <= 63.f) ? 1.f : 0.f;
      const float v01 = (x0 >= 0.f && x0 <= 63.f && y1 >= 0.f && y1 <= 63.f) ? 1.f : 0.f;
      const float v11 = (x1 >= 0.f && x1 <= 63.f && y1 >= 0.f && y1 <= 63.f) ? 1.f : 0.f;
      w00 = (1.f - wx) * (1.f - wy) * v00;
      w10 = wx * (1.f - wy) * v10;
      w01 = (1.f - wx) * wy * v01;
      w11 = wx * wy * v11;
      const int x0i = (int)fminf(fmaxf(x0, 0.f), 63.f);
      const int x1i = (int)fminf(fmaxf(x1, 0.f), 63.f);
      const int y0i = (int)fminf(fmaxf(y0, 0.f), 63.f);
      const int y1i = (int)fminf(fmaxf(y1, 0.f), 63.f);
      const int mb = m * kIMS2;
      i00 = mb + (y0i * 64 + x0i) * kCP;
      i10 = mb + (y0i * 64 + x1i) * kCP;
      i01 = mb + (y1i * 64 + x0i) * kCP;
      i11 = mb + (y1i * 64 + x1i) * kCP;
    }
    sI2[tid][0] = i00; sI2[tid][1] = i10; sI2[tid][2] = i01; sI2[tid][3] = i11;
    sW2[tid][0] = w00; sW2[tid][1] = w10; sW2[tid][2] = w01; sW2[tid][3] = w11;
  }
  __syncthreads();

  // staging: wave wv handles l = wv*4+q; lane strides float4 groups
  const int lane = tid & 63, wv = tid >> 6;
#pragma unroll
  for (int q = 0; q < 4; ++q) {
    const int l = (wv << 2) + q;
    const float a0 = sW2[l][0], a1 = sW2[l][1], a2 = sW2[l][2], a3 = sW2[l][3];
    const int b0 = sI2[l][0], b1 = sI2[l][1], b2 = sI2[l][2], b3 = sI2[l][3];
    for (int g = lane; g < kNG; g += 64) {
      const int c4 = g << 2;
      const float4 t0 = *(const float4*)&imgt[b0 + c4];
      const float4 t1 = *(const float4*)&imgt[b1 + c4];
      const float4 t2 = *(const float4*)&imgt[b2 + c4];
      const float4 t3 = *(const float4*)&imgt[b3 + c4];
      float4 r;
      r.x = fmaf(t0.x, a0, fmaf(t1.x, a1, fmaf(t2.x, a2, t3.x * a3)));
      r.y = fmaf(t0.y, a0, fmaf(t1.y, a1, fmaf(t2.y, a2, t3.y * a3)));
      r.z = fmaf(t0.z, a0, fmaf(t1.z, a1, fmaf(t2.z, a2, t3.z * a3)));
      r.w = fmaf(t0.w, a0, fmaf(t1.w, a1, fmaf(t2.w, a2, t3.w * a3)));
      *(float4*)&ctx[l][c4] = r;
    }
  }
  __syncthreads();

  // scores: 16 groups of 16 lanes; group g owns l=g, computes 3 heads
  const int g16 = tid >> 4, l16 = tid & 15;
  const float* qkn = qk + (size_t)n * kLDQ;
  float p0 = 0.f, p1 = 0.f, p2 = 0.f;
  auto dot4 = [&](int c4) {
    const float4 cv = *(const float4*)&ctx[g16][c4];
    const float4 q0 = *(const float4*)&qkn[c4];
    const float4 q1 = *(const float4*)&qkn[kCP + c4];
    const float4 q2 = *(const float4*)&qkn[2 * kCP + c4];
    p0 = fmaf(cv.x, q0.x, fmaf(cv.y, q0.y, fmaf(cv.z, q0.z, fmaf(cv.w, q0.w, p0))));
    p1 = fmaf(cv.x, q1.x, fmaf(cv.y, q1.y, fmaf(cv.z, q1.z, fmaf(cv.w, q1.w, p1))));
    p2 = fmaf(cv.x, q2.x, fmaf(cv.y, q2.y, fmaf(cv.z, q2.z, fmaf(cv.w, q2.w, p2))));
  };
#pragma unroll
  for (int it = 0; it < 12; ++it) dot4((l16 + (it << 4)) << 2);
  if (l16 < 2) dot4((192 + l16) << 2);  // tail groups (pad contributes 0)
#pragma unroll
  for (int off = 8; off; off >>= 1) {
    p0 += __shfl_down(p0, off, 16);
    p1 += __shfl_down(p1, off, 16);
    p2 += __shfl_down(p2, off, 16);
  }
  if (l16 == 0) {
    ssc[g16] = p0 + qbk[n * 3 + 0];
    ssc[16 + g16] = p1 + qbk[n * 3 + 1];
    ssc[32 + g16] = p2 + qbk[n * 3 + 2];
  }
  __syncthreads();
  if (tid < 3) {
    float mx = ssc[tid * 16];
#pragma unroll
    for (int l = 1; l < kL; ++l) mx = fmaxf(mx, ssc[tid * 16 + l]);
    float e[kL];
    float sum = 0.f;
#pragma unroll
    for (int l = 0; l < kL; ++l) {
      e[l] = expf(ssc[tid * 16 + l] - mx);
      sum += e[l];
    }
    const float inv = 1.f / sum;
#pragma unroll
    for (int l = 0; l < kL; ++l) swt[tid * 16 + l] = e[l] * inv;
  }
  __syncthreads();

  // PV: thread owns one float4 channel group; split-store 3 heads
  if (tid < kNG) {
    const int c4 = tid << 2;
    float4 o0{0.f, 0.f, 0.f, 0.f}, o1{0.f, 0.f, 0.f, 0.f}, o2{0.f, 0.f, 0.f, 0.f};
#pragma unroll
    for (int l = 0; l < kL; ++l) {
      const float4 cv = *(const float4*)&ctx[l][c4];
      const float s0 = swt[l], s1 = swt[16 + l], s2 = swt[32 + l];
      o0.x = fmaf(cv.x, s0, o0.x); o0.y = fmaf(cv.y, s0, o0.y);
      o0.z = fmaf(cv.z, s0, o0.z); o0.w = fmaf(cv.w, s0, o0.w);
      o1.x = fmaf(cv.x, s1, o1.x); o1.y = fmaf(cv.y, s1, o1.y);
      o1.z = fmaf(cv.z, s1, o1.z); o1.w = fmaf(cv.w, s1, o1.w);
      o2.x = fmaf(cv.x, s2, o2.x); o2.y = fmaf(cv.y, s2, o2.y);
      o2.z = fmaf(cv.z, s2, o2.z); o2.w = fmaf(cv.w, s2, o2.w);
    }
    const size_t base = (size_t)n * kLDA;
    float4 ov[3] = {o0, o1, o2};
#pragma unroll
    for (int h = 0; h < 3; ++h) {
      ushort4 hi, lo;
      hi.x = f2bf(ov[h].x); lo.x = f2bf(ov[h].x - bf2f(hi.x));
      hi.y = f2bf(ov[h].y); lo.y = f2bf(ov[h].y - bf2f(hi.y));
      hi.z = f2bf(ov[h].z); lo.z = f2bf(ov[h].z - bf2f(hi.z));
      hi.w = f2bf(ov[h].w); lo.w = f2bf(ov[h].w - bf2f(hi.w));
      *(ushort4*)&whi[base + h * kKP + c4] = hi;
      *(ushort4*)&wlo[base + h * kKP + c4] = lo;
    }
  }
  if (tid < 72) {  // zero K-pad 776..799 per head
    const int h = tid / 24, k2 = kCP + tid % 24;
    const size_t pz = (size_t)n * kLDA + h * kKP + k2;
    whi[pz] = 0;
    wlo[pz] = 0;
  }
}

// ---- OLD fused sample+attn (strided tier-B / f32 tier-C fallback) ---------
template <bool SPLIT>
__global__ void __launch_bounds__(256) sample_attn_kernel(
    const float* __restrict__ src, const int pixstride, const int cstride,
    const float* __restrict__ w2c, const float* __restrict__ Kin,
    const float* __restrict__ qk, const int ldq, const int hp,
    const float* __restrict__ qbk, const int plane, float* __restrict__ wctx,
    unsigned short* __restrict__ whi, unsigned short* __restrict__ wlo) {
  __shared__ float ctx[kL * kC];
  __shared__ float su[kL], sv[kL], smk[kL];
  __shared__ float spart[4][48];
  __shared__ float ssc[48];
  __shared__ float swt[48];
  const int n = blockIdx.x, i = n >> 6, j = n & 63, tid = threadIdx.x;

  if (tid < kL) {
    const int s = tid >> 2, m = tid & 3;
    const float Xi = -1.f + 2.f * i / 63.f;
    const float Xj = -1.f + 2.f * j / 63.f;
    const float Ts = -1.f + 2.f * s / 3.f;
    float px, py, pz;
    if (plane == 0) { px = Xj; py = Xi; pz = Ts; }
    else if (plane == 1) { px = Xj; py = Ts; pz = Xi; }
    else { px = Ts; py = Xj; pz = Xi; }
    const float* W = w2c + m * 16;
    const float c0 = W[0] * px + W[1] * py + W[2] * pz + W[3];
    const float c1 = W[4] * px + W[5] * py + W[6] * pz + W[7];
    const float c2 = W[8] * px + W[9] * py + W[10] * pz + W[11];
    const float* Km = Kin + m * 9;
    const float un = Km[0] * c0 + Km[1] * c1 + Km[2] * c2;
    const float vn = Km[3] * c0 + Km[4] * c1 + Km[5] * c2;
    const float ds = c2 + 1e-8f;
    const float u = un / ds, v = vn / ds;
    const float mk =
        (c2 > 0.f && u >= 0.f && u < 64.f && v >= 0.f && v < 64.f) ? 1.f : 0.f;
    su[tid] = u; sv[tid] = v; smk[tid] = mk;
  }
  __syncthreads();

  for (int l = 0; l < kL; ++l) {
    const int m = l & 3;
    const float u = su[l], v = sv[l], mk = smk[l];
    float w00 = 0.f, w10 = 0.f, w01 = 0.f, w11 = 0.f;
    int i00 = 0, i10 = 0, i01 = 0, i11 = 0;
    if (mk != 0.f) {
      const float gx = 2.f * (u / 63.f) - 1.f;
      const float gy = 2.f * (v / 63.f) - 1.f;
      const float ix = (gx + 1.f) * 0.5f * 63.f;
      const float iy = (gy + 1.f) * 0.5f * 63.f;
      const float x0 = floorf(ix), y0 = floorf(iy);
      const float x1 = x0 + 1.f, y1 = y0 + 1.f;
      const float wx = ix - x0, wy = iy - y0;
      const float v00 = (x0 >= 0.f && x0 <= 63.f && y0 >= 0.f && y0 <= 63.f) ? 1.f : 0.f;
      const float v10 = (x1 >= 0.f && x1 <= 63.f && y0 >= 0.f && y0 <= 63.f) ? 1.f : 0.f;
      const float v01 = (x0 >= 0.f && x0 <= 63.f && y1 >= 0.f && y1 <= 63.f) ? 1.f : 0.f;
      const float v11 = (x1 >= 0.f && x1 <= 63.f && y1 >= 0.f && y1 <= 63.f) ? 1.f : 0.f;
      w00 = (1.f - wx) * (1.f - wy) * v00;
      w10 = wx * (1.f - wy) * v10;
      w01 = (1.f - wx) * wy * v01;
      w11 = wx * wy * v11;
      const int x0i = (int)fminf(fmaxf(x0, 0.f), 63.f);
      const int x1i = (int)fminf(fmaxf(x1, 0.f), 63.f);
      const int y0i = (int)fminf(fmaxf(y0, 0.f), 63.f);
      const int y1i = (int)fminf(fmaxf(y1, 0.f), 63.f);
      const int mb = m * kImgMStride;
      i00 = mb + (y0i * 64 + x0i) * pixstride;
      i10 = mb + (y0i * 64 + x1i) * pixstride;
      i01 = mb + (y1i * 64 + x0i) * pixstride;
      i11 = mb + (y1i * 64 + x1i) * pixstride;
    }
    for (int c = tid; c < kC; c += 256) {
      const int cs = c * cstride;
      ctx[l * kC + c] = src[i00 + cs] * w00 + src[i10 + cs] * w10 +
                        src[i01 + cs] * w01 + src[i11 + cs] * w11;
    }
  }
  __syncthreads();

  float acc[48];
#pragma unroll
  for (int t = 0; t < 48; ++t) acc[t] = 0.f;
  const float* qkn = qk + (size_t)n * ldq;
  for (int c = tid; c < kC; c += 256) {
    const float q0 = qkn[c], q1 = qkn[hp + c], q2 = qkn[2 * hp + c];
#pragma unroll
    for (int l = 0; l < kL; ++l) {
      const float cv = ctx[l * kC + c];
      acc[l] = fmaf(cv, q0, acc[l]);
      acc[16 + l] = fmaf(cv, q1, acc[16 + l]);
      acc[32 + l] = fmaf(cv, q2, acc[32 + l]);
    }
  }
#pragma unroll
  for (int t = 0; t < 48; ++t) {
    float x = acc[t];
#pragma unroll
    for (int off = 32; off; off >>= 1) x += __shfl_down(x, off);
    acc[t] = x;
  }
  if ((tid & 63) == 0) {
#pragma unroll
    for (int t = 0; t < 48; ++t) spart[tid >> 6][t] = acc[t];
  }
  __syncthreads();
  if (tid < 48)
    ssc[tid] = spart[0][tid] + spart[1][tid] + spart[2][tid] + spart[3][tid] +
               qbk[n * 3 + (tid >> 4)];
  __syncthreads();
  if (tid < 3) {
    float mx = ssc[tid * 16];
#pragma unroll
    for (int l = 1; l < kL; ++l) mx = fmaxf(mx, ssc[tid * 16 + l]);
    float e[kL];
    float sum = 0.f;
#pragma unroll
    for (int l = 0; l < kL; ++l) {
      e[l] = expf(ssc[tid * 16 + l] - mx);
      sum += e[l];
    }
    const float inv = 1.f / sum;
#pragma unroll
    for (int l = 0; l < kL; ++l) swt[tid * 16 + l] = e[l] * inv;
  }
  __syncthreads();

  for (int c = tid; c < kC; c += 256) {
    float o0 = 0.f, o1 = 0.f, o2 = 0.f;
#pragma unroll
    for (int l = 0; l < kL; ++l) {
      const float cv = ctx[l * kC + c];
      o0 = fmaf(swt[l], cv, o0);
      o1 = fmaf(swt[16 + l], cv, o1);
      o2 = fmaf(swt[32 + l], cv, o2);
    }
    if (SPLIT) {
      const size_t base = (size_t)n * kLDA;
      unsigned short t0 = f2bf(o0), t1 = f2bf(o1), t2 = f2bf(o2);
      whi[base + c] = t0;
      whi[base + kKP + c] = t1;
      whi[base + 2 * kKP + c] = t2;
      wlo[base + c] = f2bf(o0 - bf2f(t0));
      wlo[base + kKP + c] = f2bf(o1 - bf2f(t1));
      wlo[base + 2 * kKP + c] = f2bf(o2 - bf2f(t2));
    } else {
      float* wn = wctx + (size_t)n * kQD;
      wn[c] = o0;
      wn[kC + c] = o1;
      wn[2 * kC + c] = o2;
    }
  }
  if (SPLIT && tid < 3 * (kKP - kC)) {
    const int h = tid / (kKP - kC), k = kC + tid % (kKP - kC);
    const size_t p = (size_t)n * kLDA + h * kKP + k;
    whi[p] = 0; wlo[p] = 0;
  }
}

// ---- bf16-split MFMA GEMM --------------------------------------------------
// A: [4096][2400] bf16 splits; B: [3][896][800] bf16 splits (K-contiguous).
// C row stride ldc, head pitch hpitch; PADZ zero-fills cols 771..775.
template <bool BIAS, bool PADZ>
__global__ void __launch_bounds__(256) gemm_mfma(
    const unsigned short* __restrict__ Ahi, const unsigned short* __restrict__ Alo,
    const unsigned short* __restrict__ Bhi, const unsigned short* __restrict__ Blo,
    float* __restrict__ C, const float* __restrict__ bias, const int ldc,
    const int hpitch) {
  __shared__ unsigned short smA[2][128 * 32];
  __shared__ unsigned short smB[2][128 * 32];
  const int h = blockIdx.z;
  const int m0 = blockIdx.y * 128;
  const int n0 = blockIdx.x * 128;
  const int tid = threadIdx.x;
  const int lane = tid & 63, w = tid >> 6;
  const int wm = w >> 1, wn = w & 1;

  const int sr0 = w * 16 + (lane >> 2);
  const int ss = lane & 3;
  size_t aoff[2], boff[2];
  int ldsb[2];
#pragma unroll
  for (int p = 0; p < 2; ++p) {
    const int r = p * 64 + sr0;
    const int kl = (ss ^ ((r >> 1) & 3)) * 8;
    aoff[p] = (size_t)(m0 + r) * kLDA + (size_t)h * kKP + kl;
    boff[p] = ((size_t)h * kBROWS + (n0 + r)) * kKP + kl;
    ldsb[p] = (p * 64 + w * 16) * 32;
  }

  int offA[4], offB[4];
#pragma unroll
  for (int i = 0; i < 4; ++i) {
    const int ra = wm * 64 + i * 16 + (lane & 15);
    offA[i] = ra * 32 + (((lane >> 4) ^ ((ra >> 1) & 3)) << 3);
    const int rb = wn * 64 + i * 16 + (lane & 15);
    offB[i] = rb * 32 + (((lane >> 4) ^ ((rb >> 1) & 3)) << 3);
  }

  f32x4 acc[4][4];
#pragma unroll
  for (int i = 0; i < 4; ++i)
#pragma unroll
    for (int j = 0; j < 4; ++j) acc[i][j] = f32x4{0.f, 0.f, 0.f, 0.f};

  for (int k0 = 0; k0 < kKP; k0 += 32) {
#pragma unroll
    for (int p = 0; p < 2; ++p) {
      gload16(Ahi + aoff[p] + k0, &smA[0][ldsb[p]]);
      gload16(Alo + aoff[p] + k0, &smA[1][ldsb[p]]);
      gload16(Bhi + boff[p] + k0, &smB[0][ldsb[p]]);
      gload16(Blo + boff[p] + k0, &smB[1][ldsb[p]]);
    }
    __syncthreads();
    bf16x8 ah[4], al[4], bh[4], bl[4];
#pragma unroll
    for (int i = 0; i < 4; ++i) {
      ah[i] = *(const bf16x8*)&smA[0][offA[i]];
      al[i] = *(const bf16x8*)&smA[1][offA[i]];
      bh[i] = *(const bf16x8*)&smB[0][offB[i]];
      bl[i] = *(const bf16x8*)&smB[1][offB[i]];
    }
#pragma unroll
    for (int i = 0; i < 4; ++i)
#pragma unroll
      for (int j = 0; j < 4; ++j)
        acc[i][j] =
            __builtin_amdgcn_mfma_f32_16x16x32_bf16(ah[i], bh[j], acc[i][j], 0, 0, 0);
#pragma unroll
    for (int i = 0; i < 4; ++i)
#pragma unroll
      for (int j = 0; j < 4; ++j)
        acc[i][j] =
            __builtin_amdgcn_mfma_f32_16x16x32_bf16(ah[i], bl[j], acc[i][j], 0, 0, 0);
#pragma unroll
    for (int i = 0; i < 4; ++i)
#pragma unroll
      for (int j = 0; j < 4; ++j)
        acc[i][j] =
            __builtin_amdgcn_mfma_f32_16x16x32_bf16(al[i], bh[j], acc[i][j], 0, 0, 0);
    __syncthreads();
  }

  const int rbase = m0 + wm * 64;
  const int cbase = n0 + wn * 64;
#pragma unroll
  for (int i = 0; i < 4; ++i) {
#pragma unroll
    for (int j = 0; j < 4; ++j) {
      const int col = cbase + j * 16 + (lane & 15);
      if (col < kC) {
        const float bb = BIAS ? bias[h * kC + col] : 0.f;
#pragma unroll
        for (int r = 0; r < 4; ++r) {
          const int row = rbase + i * 16 + (lane >> 4) * 4 + r;
          C[(size_t)row * ldc + h * hpitch + col] = acc[i][j][r] + bb;
        }
      } else if (PADZ && col < kCP) {
#pragma unroll
        for (int r = 0; r < 4; ++r) {
          const int row = rbase + i * 16 + (lane >> 4) * 4 + r;
          C[(size_t)row * ldc + h * hpitch + col] = 0.f;
        }
      }
    }
  }
}

// ---- tier-C fallback f32 GEMM ----------------------------------------------
template <bool BT, bool BIAS>
__global__ void __launch_bounds__(256) gemm_f32(
    const float* __restrict__ A, const float* __restrict__ B,
    float* __restrict__ Cp, const float* __restrict__ bias, const int M,
    const int N, const int K, const int lda, const int ldb, const int ldc,
    const int hstride) {
  constexpr int BM = 128, BN = 64, BK = 16;
  __shared__ float As[BK][BM + 4];
  __shared__ float Bs[BK][BN + 4];
  const int hoff = blockIdx.z * hstride;
  const int m0 = blockIdx.y * BM, n0 = blockIdx.x * BN;
  const int tid = threadIdx.x;
  const int ty = tid >> 4, tx = tid & 15;
  float acc[8][4];
#pragma unroll
  for (int r = 0; r < 8; ++r)
#pragma unroll
    for (int c = 0; c < 4; ++c) acc[r][c] = 0.f;
  for (int k0 = 0; k0 < K; k0 += BK) {
#pragma unroll
    for (int p = 0; p < 8; ++p) {
      const int idx = tid + p * 256;
      const int mm = idx >> 4, kk = idx & 15;
      float v = 0.f;
      if (k0 + kk < K) v = A[(size_t)(m0 + mm) * lda + hoff + k0 + kk];
      As[kk][mm] = v;
    }
    if (BT) {
#pragma unroll
      for (int p = 0; p < 4; ++p) {
        const int idx = tid + p * 256;
        const int jj = idx >> 4, kk = idx & 15;
        float v = 0.f;
        if ((n0 + jj) < N && (k0 + kk) < K)
          v = B[(size_t)(n0 + jj) * ldb + hoff + k0 + kk];
        Bs[kk][jj] = v;
      }
    } else {
#pragma unroll
      for (int p = 0; p < 4; ++p) {
        const int idx = tid + p * 256;
        const int kk = idx >> 6, jj = idx & 63;
        float v = 0.f;
        if ((n0 + jj) < N && (k0 + kk) < K)
          v = B[(size_t)(k0 + kk) * ldb + hoff + n0 + jj];
        Bs[kk][jj] = v;
      }
    }
    __syncthreads();
#pragma unroll
    for (int kk = 0; kk < BK; ++kk) {
      float a[8], b[4];
#pragma unroll
      for (int r = 0; r < 8; ++r) a[r] = As[kk][ty * 8 + r];
#pragma unroll
      for (int c = 0; c < 4; ++c) b[c] = Bs[kk][tx * 4 + c];
#pragma unroll
      for (int r = 0; r < 8; ++r)
#pragma unroll
        for (int c = 0; c < 4; ++c) acc[r][c] = fmaf(a[r], b[c], acc[r][c]);
    }
    __syncthreads();
  }
#pragma unroll
  for (int r = 0; r < 8; ++r) {
    const int mm = m0 + ty * 8 + r;
    if (mm >= M) continue;
#pragma unroll
    for (int c = 0; c < 4; ++c) {
      const int jj = n0 + tx * 4 + c;
      if (jj < N) {
        float v = acc[r][c];
        if (BIAS) v += bias[hoff + jj];
        Cp[(size_t)mm * ldc + hoff + jj] = v;
      }
    }
  }
}

// ---------------------------------------------------------------------------
extern "C" void kernel_launch(void* const* d_in, const int* in_sizes, int n_in,
                              void* d_out, int out_size, void* d_ws,
                              size_t ws_size, hipStream_t stream) {
  const float* imgf = (const float*)d_in[0];
  const float* c2w = (const float*)d_in[2];
  const float* Kin = (const float*)d_in[3];
  const float* qpl[3] = {(const float*)d_in[5], (const float*)d_in[6],
                         (const float*)d_in[7]};
  const float* Wk = (const float*)d_in[8];
  const float* bk = (const float*)d_in[9];
  const float* Wv = (const float*)d_in[10];
  const float* bv = (const float*)d_in[11];
  const float* ln_g = (const float*)d_in[12];
  const float* ln_b = (const float*)d_in[13];
  float* out = (float*)d_out;
  char* wsb = (char*)d_ws;

  const size_t QN_FLOATS = (size_t)kNPIX * kQD;     // out plane stride
  const size_t QKB_FLOATS = (size_t)kNPIX * kLDQ;   // padded qkb
  const size_t IMGT_FLOATS = (size_t)kNV * kIMS2;   // padded imgt
  const size_t W_ELEMS = (size_t)3 * kBROWS * kKP;
  const size_t A_ELEMS = (size_t)kNPIX * kLDA;

  size_t off = 0;
  auto take = [&](size_t bytes) {
    size_t o = off;
    off = (off + bytes + 511) & ~(size_t)511;
    return o;
  };
  const size_t o_w2c = take(64 * 4);
  const size_t o_qbk = take((size_t)kNPIX * 3 * 4);
  const size_t o_qkb = take(QKB_FLOATS * 4);
  const size_t o_wkhi = take(W_ELEMS * 2);
  const size_t o_wklo = take(W_ELEMS * 2);
  const size_t o_wvthi = take(W_ELEMS * 2);
  const size_t o_wvtlo = take(W_ELEMS * 2);
  const size_t o_ahi = take(A_ELEMS * 2);
  const size_t o_alo = take(A_ELEMS * 2);
  const size_t need_B = off;
  const size_t o_imgt = take(IMGT_FLOATS * 4);
  const size_t need_A = off;

  const int tier = (ws_size >= need_A) ? 0 : (ws_size >= need_B) ? 1 : 2;

  if (tier <= 1) {
    float* w2c = (float*)(wsb + o_w2c);
    float* qbk = (float*)(wsb + o_qbk);
    float* qkb = (float*)(wsb + o_qkb);
    unsigned short* wkhi = (unsigned short*)(wsb + o_wkhi);
    unsigned short* wklo = (unsigned short*)(wsb + o_wklo);
    unsigned short* wvthi = (unsigned short*)(wsb + o_wvthi);
    unsigned short* wvtlo = (unsigned short*)(wsb + o_wvtlo);
    unsigned short* ahi = (unsigned short*)(wsb + o_ahi);
    unsigned short* alo = (unsigned short*)(wsb + o_alo);
    float* imgt = (float*)(wsb + o_imgt);

    invert4_kernel<<<1, 64, 0, stream>>>(c2w, w2c);
    prep_wk_kernel<<<dim3(kBROWS, 3), 256, 0, stream>>>(Wk, wkhi, wklo);
    prep_wvt_kernel<<<dim3(13, 14, 3), 256, 0, stream>>>(Wv, wvthi, wvtlo);
    if (tier == 0)
      transpose_img_kernel<<<dim3(64, kNV), 256, 0, stream>>>(imgf, imgt);

    for (int p = 0; p < 3; ++p) {
      const float* qo0 = (p == 0) ? qpl[1] : qpl[0];
      const float* qo1 = (p == 2) ? qpl[1] : qpl[2];
      build_q_kernel<true><<<kNPIX, 256, 0, stream>>>(
          qpl[p], qo0, qo1, p, ln_g, ln_b, bk, nullptr, ahi, alo, qbk);
      gemm_mfma<false, true><<<dim3(7, 32, 3), 256, 0, stream>>>(
          ahi, alo, wkhi, wklo, qkb, nullptr, kLDQ, kCP);
      if (tier == 0) {
        sample_attn2_kernel<<<kNPIX, 256, 0, stream>>>(imgt, w2c, Kin, qkb,
                                                       qbk, p, ahi, alo);
      } else {
        sample_attn_kernel<true><<<kNPIX, 256, 0, stream>>>(
            imgf, 1, kG * kG, w2c, Kin, qkb, kLDQ, kCP, qbk, p, nullptr, ahi,
            alo);
      }
      gemm_mfma<true, false><<<dim3(7, 32, 3), 256, 0, stream>>>(
          ahi, alo, wvthi, wvtlo, out + (size_t)p * QN_FLOATS, bv, kQD, kC);
    }
  } else {
    // tier C: f32 fallback
    float* ws = (float*)d_ws;
    const size_t OFF_QBK = 64;
    const size_t OFF_BIG = OFF_QBK + (size_t)kNPIX * 3;
    float* w2c = ws;
    float* qbk = ws + OFF_QBK;
    float* qn = ws + OFF_BIG;
    float* qkb = qn + QN_FLOATS;

    invert4_kernel<<<1, 64, 0, stream>>>(c2w, w2c);
    for (int p = 0; p < 3; ++p) {
      const float* qo0 = (p == 0) ? qpl[1] : qpl[0];
      const float* qo1 = (p == 2) ? qpl[1] : qpl[2];
      build_q_kernel<false><<<kNPIX, 256, 0, stream>>>(
          qpl[p], qo0, qo1, p, ln_g, ln_b, bk, qn, nullptr, nullptr, qbk);
      gemm_f32<true, false><<<dim3(13, 32, 3), 256, 0, stream>>>(
          qn, Wk, qkb, nullptr, kNPIX, kC, kC, kQD, kQD, kQD, kC);
      sample_attn_kernel<false><<<kNPIX, 256, 0, stream>>>(
          imgf, 1, kG * kG, w2c, Kin, qkb, kQD, kC, qbk, p, qn, nullptr,
          nullptr);
      gemm_f32<false, true><<<dim3(13, 32, 3), 256, 0, stream>>>(
          qn, Wv, out + (size_t)p * QN_FLOATS, bv, kNPIX, kC, kC, kQD, kQD,
          kQD, kC);
    }
  }
}

// Round 4
// 891.657 us; speedup vs baseline: 3.3037x; 1.1973x over previous
//
#include <hip/hip_runtime.h>
#include <math.h>

// ---------------------------------------------------------------------------
// Round 4: batch all 3 planes into single dispatches (build_q, gemm_qk,
// sample_attn, gemm_out) + XCD-panel-grouped block swizzle in the MFMA GEMM
// (all 7 n-blocks of an A-panel share one XCD L2). Tiered ws fallback to the
// per-plane round-3 path, strided path, and f32 path.
// ---------------------------------------------------------------------------

constexpr int kG = 64, kS = 4, kC = 771, kNV = 4;
constexpr int kQD = 2313;                  // 3 * kC
constexpr int kNPIX = 4096;                // kG * kG
constexpr int kL = 16;                     // kS * kNV
constexpr int kImgMStride = kC * kG * kG;  // view stride, original layout
constexpr int kKP = 800;                   // padded per-head K (771 -> 800)
constexpr int kLDA = 2400;                 // 3 heads * 800
constexpr int kBROWS = 896;                // padded B rows (771 -> 896)
constexpr int kCP = 776;                   // padded channels (float4)
constexpr int kNG = kCP / 4;               // 194 float4 groups
constexpr int kLDQ = 3 * kCP;              // 2328 qkb row stride
constexpr int kIMS2 = kNPIX * kCP;         // padded view stride

constexpr size_t kQKB_FLOATS = (size_t)kNPIX * kLDQ;  // per-slot qkb
constexpr size_t kA_ELEMS = (size_t)kNPIX * kLDA;     // per-slot A splits
constexpr size_t kQN_FLOATS = (size_t)kNPIX * kQD;    // out plane stride

using bf16x8 = __attribute__((ext_vector_type(8))) short;
using f32x4 = __attribute__((ext_vector_type(4))) float;

__device__ __forceinline__ unsigned short f2bf(float x) {
  unsigned int u = __float_as_uint(x);
  u = (u + 0x7FFFu + ((u >> 16) & 1u)) >> 16;
  return (unsigned short)u;
}
__device__ __forceinline__ float bf2f(unsigned short h) {
  return __uint_as_float(((unsigned int)h) << 16);
}
__device__ __forceinline__ void gload16(const unsigned short* g,
                                        unsigned short* l) {
  __builtin_amdgcn_global_load_lds(
      (const __attribute__((address_space(1))) void*)g,
      (__attribute__((address_space(3))) void*)l, 16, 0, 0);
}

// ---- tiny 4x4 batched inverse (c2w -> w2c) --------------------------------
__global__ void invert4_kernel(const float* __restrict__ c2w,
                               float* __restrict__ w2c) {
  const int m = threadIdx.x;
  if (m >= kNV) return;
  float a[4][8];
  for (int r = 0; r < 4; ++r)
    for (int c = 0; c < 4; ++c) {
      a[r][c] = c2w[m * 16 + r * 4 + c];
      a[r][4 + c] = (r == c) ? 1.f : 0.f;
    }
  for (int col = 0; col < 4; ++col) {
    int piv = col;
    float best = fabsf(a[col][col]);
    for (int r = col + 1; r < 4; ++r) {
      float t = fabsf(a[r][col]);
      if (t > best) { best = t; piv = r; }
    }
    if (piv != col)
      for (int c = 0; c < 8; ++c) {
        float t = a[col][c]; a[col][c] = a[piv][c]; a[piv][c] = t;
      }
    const float inv = 1.f / a[col][col];
    for (int c = 0; c < 8; ++c) a[col][c] *= inv;
    for (int r = 0; r < 4; ++r)
      if (r != col) {
        const float f = a[r][col];
        for (int c = 0; c < 8; ++c) a[r][c] -= f * a[col][c];
      }
  }
  for (int r = 0; r < 4; ++r)
    for (int c = 0; c < 4; ++c) w2c[m * 16 + r * 4 + c] = a[r][4 + c];
}

// ---- image transpose [NV,C,H,W] -> [NV,H,W,776] (zero pad 771..775) ------
__global__ void __launch_bounds__(256) transpose_img_kernel(
    const float* __restrict__ img, float* __restrict__ out) {
  __shared__ float t[64][65];
  const int y = blockIdx.x, m = blockIdx.y, tid = threadIdx.x;
  const size_t obase = ((size_t)m * kNPIX + (size_t)y * 64) * kCP;
  for (int c0 = 0; c0 < kC; c0 += 64) {
    const int cw = (kC - c0) < 64 ? (kC - c0) : 64;
    for (int idx = tid; idx < cw * 64; idx += 256) {
      const int cl = idx >> 6, x = idx & 63;
      t[cl][x] = img[(((size_t)m * kC + c0 + cl) * 64 + y) * 64 + x];
    }
    __syncthreads();
    for (int idx = tid; idx < 64 * 64; idx += 256) {
      const int x = idx >> 6, cl = idx & 63;
      if (cl < cw) out[obase + (size_t)x * kCP + c0 + cl] = t[cl][x];
    }
    __syncthreads();
  }
  for (int idx = tid; idx < 64 * 8; idx += 256) {
    const int x = idx >> 3, c = 768 + (idx & 7);
    if (c >= kC && c < kCP) out[obase + (size_t)x * kCP + c] = 0.f;
  }
}

// ---- weight prep: Wk split (no transpose), Wv transpose+split -------------
__global__ void __launch_bounds__(256) prep_wk_kernel(
    const float* __restrict__ Wk, unsigned short* __restrict__ hi,
    unsigned short* __restrict__ lo) {
  const int c = blockIdx.x, h = blockIdx.y;  // c in [0,896)
  const size_t base = ((size_t)h * kBROWS + c) * kKP;
  for (int k = threadIdx.x; k < kKP; k += 256) {
    float v = (c < kC && k < kC) ? Wk[(size_t)c * kQD + h * kC + k] : 0.f;
    const unsigned short a = f2bf(v);
    hi[base + k] = a;
    lo[base + k] = f2bf(v - bf2f(a));
  }
}

__global__ void __launch_bounds__(256) prep_wvt_kernel(
    const float* __restrict__ Wv, unsigned short* __restrict__ hi,
    unsigned short* __restrict__ lo) {
  __shared__ float t[64][65];
  const int k0 = blockIdx.x * 64, j0 = blockIdx.y * 64, h = blockIdx.z;
  const int tx = threadIdx.x & 63, ty4 = threadIdx.x >> 6;
  for (int ty = ty4; ty < 64; ty += 4) {
    const int k = k0 + ty, j = j0 + tx;
    t[ty][tx] = (k < kC && j < kC) ? Wv[(size_t)k * kQD + h * kC + j] : 0.f;
  }
  __syncthreads();
  for (int ty = ty4; ty < 64; ty += 4) {
    const int j = j0 + ty, k = k0 + tx;
    if (j < kBROWS && k < kKP) {
      const float v = t[tx][ty];
      const unsigned short a = f2bf(v);
      const size_t p = ((size_t)h * kBROWS + j) * kKP + k;
      hi[p] = a;
      lo[p] = f2bf(v - bf2f(a));
    }
  }
}

// ---- build query + layernorm; plane = plane_base + blockIdx.y -------------
template <bool SPLIT>
__global__ void __launch_bounds__(256) build_q_kernel(
    const float* __restrict__ q_xy, const float* __restrict__ q_xz,
    const float* __restrict__ q_yz, const int plane_base,
    const float* __restrict__ ln_g, const float* __restrict__ ln_b,
    const float* __restrict__ bk, float* __restrict__ qn,
    unsigned short* __restrict__ ahi, unsigned short* __restrict__ alo,
    float* __restrict__ qbk) {
  const int slot = blockIdx.y, plane = plane_base + slot;
  const float* qp = (plane == 0) ? q_xy : (plane == 1) ? q_xz : q_yz;
  const float* qo0 = (plane == 0) ? q_xz : q_xy;
  const float* qo1 = (plane == 2) ? q_xz : q_yz;
  const int n = blockIdx.x, i = n >> 6, j = n & 63, tid = threadIdx.x;
  __shared__ float qf[kQD];
  __shared__ int sIdx[2][4][4];
  __shared__ float sW[2][4][4];
  __shared__ float red[16];

  if (tid < 8) {
    const int part = tid >> 2, s = tid & 3;
    const float Xi = -1.f + 2.f * i / 63.f;
    const float Xj = -1.f + 2.f * j / 63.f;
    const float Ts = -1.f + 2.f * s / 3.f;
    float a, b;
    if (plane == 0) { a = part ? Xi : Xj; b = Ts; }
    else if (plane == 1) {
      if (part == 0) { a = Xj; b = Ts; } else { a = Ts; b = Xi; }
    } else { a = Ts; b = part ? Xi : Xj; }
    const float ga = fminf(fmaxf((a * 0.5f + 0.5f) * 63.f, 0.f), 63.f);
    const float gb = fminf(fmaxf((b * 0.5f + 0.5f) * 63.f, 0.f), 63.f);
    const float ix = fminf(fmaxf((ga + 1.f) * 0.5f * 63.f, 0.f), 63.f);
    const float iy = fminf(fmaxf((gb + 1.f) * 0.5f * 63.f, 0.f), 63.f);
    const float x0 = floorf(ix), y0 = floorf(iy);
    const float wx = ix - x0, wy = iy - y0;
    const int x0i = (int)x0, y0i = (int)y0;
    const int x1i = (x0i + 1 > 63) ? 63 : x0i + 1;
    const int y1i = (y0i + 1 > 63) ? 63 : y0i + 1;
    sIdx[part][s][0] = (y0i * 64 + x0i) * kC;
    sIdx[part][s][1] = (y0i * 64 + x1i) * kC;
    sIdx[part][s][2] = (y1i * 64 + x0i) * kC;
    sIdx[part][s][3] = (y1i * 64 + x1i) * kC;
    sW[part][s][0] = (1.f - wx) * (1.f - wy);
    sW[part][s][1] = wx * (1.f - wy);
    sW[part][s][2] = (1.f - wx) * wy;
    sW[part][s][3] = wx * wy;
  }
  __syncthreads();

  for (int c = tid; c < kC; c += 256) {
    qf[c] = qp[(size_t)n * kC + c];
    float a1 = 0.f, a2 = 0.f;
#pragma unroll
    for (int s = 0; s < 4; ++s) {
      a1 += qo0[sIdx[0][s][0] + c] * sW[0][s][0]
          + qo0[sIdx[0][s][1] + c] * sW[0][s][1]
          + qo0[sIdx[0][s][2] + c] * sW[0][s][2]
          + qo0[sIdx[0][s][3] + c] * sW[0][s][3];
      a2 += qo1[sIdx[1][s][0] + c] * sW[1][s][0]
          + qo1[sIdx[1][s][1] + c] * sW[1][s][1]
          + qo1[sIdx[1][s][2] + c] * sW[1][s][2]
          + qo1[sIdx[1][s][3] + c] * sW[1][s][3];
    }
    qf[kC + c] = a1 * 0.25f;
    qf[2 * kC + c] = a2 * 0.25f;
  }
  __syncthreads();

  float sm = 0.f;
  for (int idx = tid; idx < kQD; idx += 256) sm += qf[idx];
#pragma unroll
  for (int off = 32; off; off >>= 1) sm += __shfl_down(sm, off);
  if ((tid & 63) == 0) red[tid >> 6] = sm;
  __syncthreads();
  const float mu = (red[0] + red[1] + red[2] + red[3]) * (1.f / kQD);
  __syncthreads();
  float sq = 0.f;
  for (int idx = tid; idx < kQD; idx += 256) {
    const float d = qf[idx] - mu;
    sq += d * d;
  }
#pragma unroll
  for (int off = 32; off; off >>= 1) sq += __shfl_down(sq, off);
  if ((tid & 63) == 0) red[tid >> 6] = sq;
  __syncthreads();
  const float var = (red[0] + red[1] + red[2] + red[3]) * (1.f / kQD);
  const float rstd = 1.f / sqrtf(var + 1e-5f);
  __syncthreads();

  float h0 = 0.f, h1 = 0.f, h2 = 0.f;
  if (SPLIT) {
    unsigned short* ah = ahi + (size_t)slot * kA_ELEMS + (size_t)n * kLDA;
    unsigned short* al = alo + (size_t)slot * kA_ELEMS + (size_t)n * kLDA;
    for (int idx = tid; idx < 3 * kKP; idx += 256) {
      int h, k;
      if (idx < kKP) { h = 0; k = idx; }
      else if (idx < 2 * kKP) { h = 1; k = idx - kKP; }
      else { h = 2; k = idx - 2 * kKP; }
      float v = 0.f;
      if (k < kC) {
        const int li = h * kC + k;
        v = (qf[li] - mu) * rstd * ln_g[li] + ln_b[li];
        const float pb = v * bk[li];
        if (h == 0) h0 += pb; else if (h == 1) h1 += pb; else h2 += pb;
      }
      const unsigned short hv = f2bf(v);
      ah[idx] = hv;
      al[idx] = f2bf(v - bf2f(hv));
    }
  } else {
    for (int idx = tid; idx < kQD; idx += 256) {
      const float v = (qf[idx] - mu) * rstd * ln_g[idx] + ln_b[idx];
      qn[(size_t)n * kQD + idx] = v;
      const float pb = v * bk[idx];
      if (idx < kC) h0 += pb;
      else if (idx < 2 * kC) h1 += pb;
      else h2 += pb;
    }
  }
#pragma unroll
  for (int off = 32; off; off >>= 1) {
    h0 += __shfl_down(h0, off);
    h1 += __shfl_down(h1, off);
    h2 += __shfl_down(h2, off);
  }
  if ((tid & 63) == 0) {
    red[(tid >> 6) * 4 + 0] = h0;
    red[(tid >> 6) * 4 + 1] = h1;
    red[(tid >> 6) * 4 + 2] = h2;
  }
  __syncthreads();
  if (tid < 3)
    qbk[((size_t)slot * kNPIX + n) * 3 + tid] =
        red[tid] + red[4 + tid] + red[8 + tid] + red[12 + tid];
}

// ---- fused sample+attn: float4 staging, group-16 scores, float4 PV --------
__global__ void __launch_bounds__(256) sample_attn2_kernel(
    const float* __restrict__ imgt, const float* __restrict__ w2c,
    const float* __restrict__ Kin, const float* __restrict__ qkb,
    const float* __restrict__ qbk, const int plane_base,
    unsigned short* __restrict__ whi, unsigned short* __restrict__ wlo) {
  __shared__ __align__(16) float ctx[kL][kCP];  // 49.7 KB
  __shared__ float sW2[kL][4];
  __shared__ int sI2[kL][4];
  __shared__ float ssc[48], swt[48];
  const int slot = blockIdx.y, plane = plane_base + slot;
  const int bid = blockIdx.x;
  const int n = ((bid & 7) << 9) | (bid >> 3);  // XCD swizzle (bijective)
  const int i = n >> 6, j = n & 63, tid = threadIdx.x;
  const float* qk = qkb + (size_t)slot * kQKB_FLOATS;

  if (tid < kL) {
    const int s = tid >> 2, m = tid & 3;
    const float Xi = -1.f + 2.f * i / 63.f;
    const float Xj = -1.f + 2.f * j / 63.f;
    const float Ts = -1.f + 2.f * s / 3.f;
    float px, py, pz;
    if (plane == 0) { px = Xj; py = Xi; pz = Ts; }
    else if (plane == 1) { px = Xj; py = Ts; pz = Xi; }
    else { px = Ts; py = Xj; pz = Xi; }
    const float* W = w2c + m * 16;
    const float c0 = W[0] * px + W[1] * py + W[2] * pz + W[3];
    const float c1 = W[4] * px + W[5] * py + W[6] * pz + W[7];
    const float c2 = W[8] * px + W[9] * py + W[10] * pz + W[11];
    const float* Km = Kin + m * 9;
    const float un = Km[0] * c0 + Km[1] * c1 + Km[2] * c2;
    const float vn = Km[3] * c0 + Km[4] * c1 + Km[5] * c2;
    const float ds = c2 + 1e-8f;
    const float u = un / ds, v = vn / ds;
    const bool mk =
        (c2 > 0.f && u >= 0.f && u < 64.f && v >= 0.f && v < 64.f);
    float w00 = 0.f, w10 = 0.f, w01 = 0.f, w11 = 0.f;
    int i00 = 0, i10 = 0, i01 = 0, i11 = 0;
    if (mk) {
      const float gx = 2.f * (u / 63.f) - 1.f;
      const float gy = 2.f * (v / 63.f) - 1.f;
      const float ix = (gx + 1.f) * 0.5f * 63.f;
      const float iy = (gy + 1.f) * 0.5f * 63.f;
      const float x0 = floorf(ix), y0 = floorf(iy);
      const float x1 = x0 + 1.f, y1 = y0 + 1.f;
      const float wx = ix - x0, wy = iy - y0;
      const float v00 = (x0 >= 0.f && x0 <= 63.f && y0 >= 0.f && y0 <= 63.f) ? 1.f : 0.f;
      const float v10 = (x1 >= 0.f && x1 <= 63.f && y0 >= 0.f && y0 <= 63.f) ? 1.f : 0.f;
      const float v01 = (x0 >= 0.f && x0 <= 63.f && y1 >= 0.f && y1 <= 63.f) ? 1.f : 0.f;
      const float v11 = (x1 >= 0.f && x1 <= 63.f && y1 >= 0.f && y1 <= 63.f) ? 1.f : 0.f;
      w00 = (1.f - wx) * (1.f - wy) * v00;
      w10 = wx * (1.f - wy) * v10;
      w01 = (1.f - wx) * wy * v01;
      w11 = wx * wy * v11;
      const int x0i = (int)fminf(fmaxf(x0, 0.f), 63.f);
      const int x1i = (int)fminf(fmaxf(x1, 0.f), 63.f);
      const int y0i = (int)fminf(fmaxf(y0, 0.f), 63.f);
      const int y1i = (int)fminf(fmaxf(y1, 0.f), 63.f);
      const int mb = m * kIMS2;
      i00 = mb + (y0i * 64 + x0i) * kCP;
      i10 = mb + (y0i * 64 + x1i) * kCP;
      i01 = mb + (y1i * 64 + x0i) * kCP;
      i11 = mb + (y1i * 64 + x1i) * kCP;
    }
    sI2[tid][0] = i00; sI2[tid][1] = i10; sI2[tid][2] = i01; sI2[tid][3] = i11;
    sW2[tid][0] = w00; sW2[tid][1] = w10; sW2[tid][2] = w01; sW2[tid][3] = w11;
  }
  __syncthreads();

  const int lane = tid & 63, wv = tid >> 6;
#pragma unroll
  for (int q = 0; q < 4; ++q) {
    const int l = (wv << 2) + q;
    const float a0 = sW2[l][0], a1 = sW2[l][1], a2 = sW2[l][2], a3 = sW2[l][3];
    const int b0 = sI2[l][0], b1 = sI2[l][1], b2 = sI2[l][2], b3 = sI2[l][3];
    for (int g = lane; g < kNG; g += 64) {
      const int c4 = g << 2;
      const float4 t0 = *(const float4*)&imgt[b0 + c4];
      const float4 t1 = *(const float4*)&imgt[b1 + c4];
      const float4 t2 = *(const float4*)&imgt[b2 + c4];
      const float4 t3 = *(const float4*)&imgt[b3 + c4];
      float4 r;
      r.x = fmaf(t0.x, a0, fmaf(t1.x, a1, fmaf(t2.x, a2, t3.x * a3)));
      r.y = fmaf(t0.y, a0, fmaf(t1.y, a1, fmaf(t2.y, a2, t3.y * a3)));
      r.z = fmaf(t0.z, a0, fmaf(t1.z, a1, fmaf(t2.z, a2, t3.z * a3)));
      r.w = fmaf(t0.w, a0, fmaf(t1.w, a1, fmaf(t2.w, a2, t3.w * a3)));
      *(float4*)&ctx[l][c4] = r;
    }
  }
  __syncthreads();

  const int g16 = tid >> 4, l16 = tid & 15;
  const float* qkn = qk + (size_t)n * kLDQ;
  float p0 = 0.f, p1 = 0.f, p2 = 0.f;
  auto dot4 = [&](int c4) {
    const float4 cv = *(const float4*)&ctx[g16][c4];
    const float4 q0 = *(const float4*)&qkn[c4];
    const float4 q1 = *(const float4*)&qkn[kCP + c4];
    const float4 q2 = *(const float4*)&qkn[2 * kCP + c4];
    p0 = fmaf(cv.x, q0.x, fmaf(cv.y, q0.y, fmaf(cv.z, q0.z, fmaf(cv.w, q0.w, p0))));
    p1 = fmaf(cv.x, q1.x, fmaf(cv.y, q1.y, fmaf(cv.z, q1.z, fmaf(cv.w, q1.w, p1))));
    p2 = fmaf(cv.x, q2.x, fmaf(cv.y, q2.y, fmaf(cv.z, q2.z, fmaf(cv.w, q2.w, p2))));
  };
#pragma unroll
  for (int it = 0; it < 12; ++it) dot4((l16 + (it << 4)) << 2);
  if (l16 < 2) dot4((192 + l16) << 2);
#pragma unroll
  for (int off = 8; off; off >>= 1) {
    p0 += __shfl_down(p0, off, 16);
    p1 += __shfl_down(p1, off, 16);
    p2 += __shfl_down(p2, off, 16);
  }
  const float* qbkn = qbk + ((size_t)slot * kNPIX + n) * 3;
  if (l16 == 0) {
    ssc[g16] = p0 + qbkn[0];
    ssc[16 + g16] = p1 + qbkn[1];
    ssc[32 + g16] = p2 + qbkn[2];
  }
  __syncthreads();
  if (tid < 3) {
    float mx = ssc[tid * 16];
#pragma unroll
    for (int l = 1; l < kL; ++l) mx = fmaxf(mx, ssc[tid * 16 + l]);
    float e[kL];
    float sum = 0.f;
#pragma unroll
    for (int l = 0; l < kL; ++l) {
      e[l] = expf(ssc[tid * 16 + l] - mx);
      sum += e[l];
    }
    const float inv = 1.f / sum;
#pragma unroll
    for (int l = 0; l < kL; ++l) swt[tid * 16 + l] = e[l] * inv;
  }
  __syncthreads();

  unsigned short* wh = whi + (size_t)slot * kA_ELEMS + (size_t)n * kLDA;
  unsigned short* wl = wlo + (size_t)slot * kA_ELEMS + (size_t)n * kLDA;
  if (tid < kNG) {
    const int c4 = tid << 2;
    float4 o0{0.f, 0.f, 0.f, 0.f}, o1{0.f, 0.f, 0.f, 0.f}, o2{0.f, 0.f, 0.f, 0.f};
#pragma unroll
    for (int l = 0; l < kL; ++l) {
      const float4 cv = *(const float4*)&ctx[l][c4];
      const float s0 = swt[l], s1 = swt[16 + l], s2 = swt[32 + l];
      o0.x = fmaf(cv.x, s0, o0.x); o0.y = fmaf(cv.y, s0, o0.y);
      o0.z = fmaf(cv.z, s0, o0.z); o0.w = fmaf(cv.w, s0, o0.w);
      o1.x = fmaf(cv.x, s1, o1.x); o1.y = fmaf(cv.y, s1, o1.y);
      o1.z = fmaf(cv.z, s1, o1.z); o1.w = fmaf(cv.w, s1, o1.w);
      o2.x = fmaf(cv.x, s2, o2.x); o2.y = fmaf(cv.y, s2, o2.y);
      o2.z = fmaf(cv.z, s2, o2.z); o2.w = fmaf(cv.w, s2, o2.w);
    }
    float4 ov[3] = {o0, o1, o2};
#pragma unroll
    for (int h = 0; h < 3; ++h) {
      ushort4 hi, lo;
      hi.x = f2bf(ov[h].x); lo.x = f2bf(ov[h].x - bf2f(hi.x));
      hi.y = f2bf(ov[h].y); lo.y = f2bf(ov[h].y - bf2f(hi.y));
      hi.z = f2bf(ov[h].z); lo.z = f2bf(ov[h].z - bf2f(hi.z));
      hi.w = f2bf(ov[h].w); lo.w = f2bf(ov[h].w - bf2f(hi.w));
      *(ushort4*)&wh[h * kKP + c4] = hi;
      *(ushort4*)&wl[h * kKP + c4] = lo;
    }
  }
  if (tid < 72) {  // zero K-pad 776..799 per head
    const int h = tid / 24, k2 = kCP + tid % 24;
    wh[h * kKP + k2] = 0;
    wl[h * kKP + k2] = 0;
  }
}

// ---- OLD fused sample+attn (strided tier / f32 tier fallback) -------------
template <bool SPLIT>
__global__ void __launch_bounds__(256) sample_attn_kernel(
    const float* __restrict__ src, const int pixstride, const int cstride,
    const float* __restrict__ w2c, const float* __restrict__ Kin,
    const float* __restrict__ qk, const int ldq, const int hp,
    const float* __restrict__ qbk, const int plane, float* __restrict__ wctx,
    unsigned short* __restrict__ whi, unsigned short* __restrict__ wlo) {
  __shared__ float ctx[kL * kC];
  __shared__ float su[kL], sv[kL], smk[kL];
  __shared__ float spart[4][48];
  __shared__ float ssc[48];
  __shared__ float swt[48];
  const int n = blockIdx.x, i = n >> 6, j = n & 63, tid = threadIdx.x;

  if (tid < kL) {
    const int s = tid >> 2, m = tid & 3;
    const float Xi = -1.f + 2.f * i / 63.f;
    const float Xj = -1.f + 2.f * j / 63.f;
    const float Ts = -1.f + 2.f * s / 3.f;
    float px, py, pz;
    if (plane == 0) { px = Xj; py = Xi; pz = Ts; }
    else if (plane == 1) { px = Xj; py = Ts; pz = Xi; }
    else { px = Ts; py = Xj; pz = Xi; }
    const float* W = w2c + m * 16;
    const float c0 = W[0] * px + W[1] * py + W[2] * pz + W[3];
    const float c1 = W[4] * px + W[5] * py + W[6] * pz + W[7];
    const float c2 = W[8] * px + W[9] * py + W[10] * pz + W[11];
    const float* Km = Kin + m * 9;
    const float un = Km[0] * c0 + Km[1] * c1 + Km[2] * c2;
    const float vn = Km[3] * c0 + Km[4] * c1 + Km[5] * c2;
    const float ds = c2 + 1e-8f;
    const float u = un / ds, v = vn / ds;
    const float mk =
        (c2 > 0.f && u >= 0.f && u < 64.f && v >= 0.f && v < 64.f) ? 1.f : 0.f;
    su[tid] = u; sv[tid] = v; smk[tid] = mk;
  }
  __syncthreads();

  for (int l = 0; l < kL; ++l) {
    const int m = l & 3;
    const float u = su[l], v = sv[l], mk = smk[l];
    float w00 = 0.f, w10 = 0.f, w01 = 0.f, w11 = 0.f;
    int i00 = 0, i10 = 0, i01 = 0, i11 = 0;
    if (mk != 0.f) {
      const float gx = 2.f * (u / 63.f) - 1.f;
      const float gy = 2.f * (v / 63.f) - 1.f;
      const float ix = (gx + 1.f) * 0.5f * 63.f;
      const float iy = (gy + 1.f) * 0.5f * 63.f;
      const float x0 = floorf(ix), y0 = floorf(iy);
      const float x1 = x0 + 1.f, y1 = y0 + 1.f;
      const float wx = ix - x0, wy = iy - y0;
      const float v00 = (x0 >= 0.f && x0 <= 63.f && y0 >= 0.f && y0 <= 63.f) ? 1.f : 0.f;
      const float v10 = (x1 >= 0.f && x1 <= 63.f && y0 >= 0.f && y0 <= 63.f) ? 1.f : 0.f;
      const float v01 = (x0 >= 0.f && x0 <= 63.f && y1 >= 0.f && y1 <= 63.f) ? 1.f : 0.f;
      const float v11 = (x1 >= 0.f && x1 <= 63.f && y1 >= 0.f && y1 <= 63.f) ? 1.f : 0.f;
      w00 = (1.f - wx) * (1.f - wy) * v00;
      w10 = wx * (1.f - wy) * v10;
      w01 = (1.f - wx) * wy * v01;
      w11 = wx * wy * v11;
      const int x0i = (int)fminf(fmaxf(x0, 0.f), 63.f);
      const int x1i = (int)fminf(fmaxf(x1, 0.f), 63.f);
      const int y0i = (int)fminf(fmaxf(y0, 0.f), 63.f);
      const int y1i = (int)fminf(fmaxf(y1, 0.f), 63.f);
      const int mb = m * kImgMStride;
      i00 = mb + (y0i * 64 + x0i) * pixstride;
      i10 = mb + (y0i * 64 + x1i) * pixstride;
      i01 = mb + (y1i * 64 + x0i) * pixstride;
      i11 = mb + (y1i * 64 + x1i) * pixstride;
    }
    for (int c = tid; c < kC; c += 256) {
      const int cs = c * cstride;
      ctx[l * kC + c] = src[i00 + cs] * w00 + src[i10 + cs] * w10 +
                        src[i01 + cs] * w01 + src[i11 + cs] * w11;
    }
  }
  __syncthreads();

  float acc[48];
#pragma unroll
  for (int t = 0; t < 48; ++t) acc[t] = 0.f;
  const float* qkn = qk + (size_t)n * ldq;
  for (int c = tid; c < kC; c += 256) {
    const float q0 = qkn[c], q1 = qkn[hp + c], q2 = qkn[2 * hp + c];
#pragma unroll
    for (int l = 0; l < kL; ++l) {
      const float cv = ctx[l * kC + c];
      acc[l] = fmaf(cv, q0, acc[l]);
      acc[16 + l] = fmaf(cv, q1, acc[16 + l]);
      acc[32 + l] = fmaf(cv, q2, acc[32 + l]);
    }
  }
#pragma unroll
  for (int t = 0; t < 48; ++t) {
    float x = acc[t];
#pragma unroll
    for (int off = 32; off; off >>= 1) x += __shfl_down(x, off);
    acc[t] = x;
  }
  if ((tid & 63) == 0) {
#pragma unroll
    for (int t = 0; t < 48; ++t) spart[tid >> 6][t] = acc[t];
  }
  __syncthreads();
  if (tid < 48)
    ssc[tid] = spart[0][tid] + spart[1][tid] + spart[2][tid] + spart[3][tid] +
               qbk[n * 3 + (tid >> 4)];
  __syncthreads();
  if (tid < 3) {
    float mx = ssc[tid * 16];
#pragma unroll
    for (int l = 1; l < kL; ++l) mx = fmaxf(mx, ssc[tid * 16 + l]);
    float e[kL];
    float sum = 0.f;
#pragma unroll
    for (int l = 0; l < kL; ++l) {
      e[l] = expf(ssc[tid * 16 + l] - mx);
      sum += e[l];
    }
    const float inv = 1.f / sum;
#pragma unroll
    for (int l = 0; l < kL; ++l) swt[tid * 16 + l] = e[l] * inv;
  }
  __syncthreads();

  for (int c = tid; c < kC; c += 256) {
    float o0 = 0.f, o1 = 0.f, o2 = 0.f;
#pragma unroll
    for (int l = 0; l < kL; ++l) {
      const float cv = ctx[l * kC + c];
      o0 = fmaf(swt[l], cv, o0);
      o1 = fmaf(swt[16 + l], cv, o1);
      o2 = fmaf(swt[32 + l], cv, o2);
    }
    if (SPLIT) {
      const size_t base = (size_t)n * kLDA;
      unsigned short t0 = f2bf(o0), t1 = f2bf(o1), t2 = f2bf(o2);
      whi[base + c] = t0;
      whi[base + kKP + c] = t1;
      whi[base + 2 * kKP + c] = t2;
      wlo[base + c] = f2bf(o0 - bf2f(t0));
      wlo[base + kKP + c] = f2bf(o1 - bf2f(t1));
      wlo[base + 2 * kKP + c] = f2bf(o2 - bf2f(t2));
    } else {
      float* wn = wctx + (size_t)n * kQD;
      wn[c] = o0;
      wn[kC + c] = o1;
      wn[2 * kC + c] = o2;
    }
  }
  if (SPLIT && tid < 3 * (kKP - kC)) {
    const int h = tid / (kKP - kC), k = kC + tid % (kKP - kC);
    const size_t p = (size_t)n * kLDA + h * kKP + k;
    whi[p] = 0; wlo[p] = 0;
  }
}

// ---- bf16-split MFMA GEMM, XCD-panel-grouped swizzle -----------------------
// blockIdx.z = slot*3 + h. Grid x,y fixed at (7,32). All 7 n-blocks of one
// A-panel share lin%8 -> same XCD L2 (A fetched ~once per panel).
template <bool BIAS, bool PADZ>
__global__ void __launch_bounds__(256) gemm_mfma(
    const unsigned short* __restrict__ Ahi, const unsigned short* __restrict__ Alo,
    const unsigned short* __restrict__ Bhi, const unsigned short* __restrict__ Blo,
    float* __restrict__ C, const float* __restrict__ bias, const int ldc,
    const int hpitch, const size_t cPlaneStride) {
  __shared__ unsigned short smA[2][128 * 32];
  __shared__ unsigned short smB[2][128 * 32];
  const int slot = blockIdx.z / 3, h = blockIdx.z % 3;
  const int t = blockIdx.y * 7 + blockIdx.x;  // 0..223
  const int xcd = t & 7, idx = t >> 3;        // idx 0..27
  const int nb = idx % 7, mb = (xcd << 2) + idx / 7;
  const int m0 = mb * 128;
  const int n0 = nb * 128;
  const unsigned short* Ah = Ahi + (size_t)slot * kA_ELEMS;
  const unsigned short* Al = Alo + (size_t)slot * kA_ELEMS;
  float* Cs = C + (size_t)slot * cPlaneStride;
  const int tid = threadIdx.x;
  const int lane = tid & 63, w = tid >> 6;
  const int wm = w >> 1, wn = w & 1;

  const int sr0 = w * 16 + (lane >> 2);
  const int ss = lane & 3;
  size_t aoff[2], boff[2];
  int ldsb[2];
#pragma unroll
  for (int p = 0; p < 2; ++p) {
    const int r = p * 64 + sr0;
    const int kl = (ss ^ ((r >> 1) & 3)) * 8;
    aoff[p] = (size_t)(m0 + r) * kLDA + (size_t)h * kKP + kl;
    boff[p] = ((size_t)h * kBROWS + (n0 + r)) * kKP + kl;
    ldsb[p] = (p * 64 + w * 16) * 32;
  }

  int offA[4], offB[4];
#pragma unroll
  for (int i = 0; i < 4; ++i) {
    const int ra = wm * 64 + i * 16 + (lane & 15);
    offA[i] = ra * 32 + (((lane >> 4) ^ ((ra >> 1) & 3)) << 3);
    const int rb = wn * 64 + i * 16 + (lane & 15);
    offB[i] = rb * 32 + (((lane >> 4) ^ ((rb >> 1) & 3)) << 3);
  }

  f32x4 acc[4][4];
#pragma unroll
  for (int i = 0; i < 4; ++i)
#pragma unroll
    for (int j = 0; j < 4; ++j) acc[i][j] = f32x4{0.f, 0.f, 0.f, 0.f};

  for (int k0 = 0; k0 < kKP; k0 += 32) {
#pragma unroll
    for (int p = 0; p < 2; ++p) {
      gload16(Ah + aoff[p] + k0, &smA[0][ldsb[p]]);
      gload16(Al + aoff[p] + k0, &smA[1][ldsb[p]]);
      gload16(Bhi + boff[p] + k0, &smB[0][ldsb[p]]);
      gload16(Blo + boff[p] + k0, &smB[1][ldsb[p]]);
    }
    __syncthreads();
    bf16x8 ah[4], al[4], bh[4], bl[4];
#pragma unroll
    for (int i = 0; i < 4; ++i) {
      ah[i] = *(const bf16x8*)&smA[0][offA[i]];
      al[i] = *(const bf16x8*)&smA[1][offA[i]];
      bh[i] = *(const bf16x8*)&smB[0][offB[i]];
      bl[i] = *(const bf16x8*)&smB[1][offB[i]];
    }
#pragma unroll
    for (int i = 0; i < 4; ++i)
#pragma unroll
      for (int j = 0; j < 4; ++j)
        acc[i][j] =
            __builtin_amdgcn_mfma_f32_16x16x32_bf16(ah[i], bh[j], acc[i][j], 0, 0, 0);
#pragma unroll
    for (int i = 0; i < 4; ++i)
#pragma unroll
      for (int j = 0; j < 4; ++j)
        acc[i][j] =
            __builtin_amdgcn_mfma_f32_16x16x32_bf16(ah[i], bl[j], acc[i][j], 0, 0, 0);
#pragma unroll
    for (int i = 0; i < 4; ++i)
#pragma unroll
      for (int j = 0; j < 4; ++j)
        acc[i][j] =
            __builtin_amdgcn_mfma_f32_16x16x32_bf16(al[i], bh[j], acc[i][j], 0, 0, 0);
    __syncthreads();
  }

  const int rbase = m0 + wm * 64;
  const int cbase = n0 + wn * 64;
#pragma unroll
  for (int i = 0; i < 4; ++i) {
#pragma unroll
    for (int j = 0; j < 4; ++j) {
      const int col = cbase + j * 16 + (lane & 15);
      if (col < kC) {
        const float bb = BIAS ? bias[h * kC + col] : 0.f;
#pragma unroll
        for (int r = 0; r < 4; ++r) {
          const int row = rbase + i * 16 + (lane >> 4) * 4 + r;
          Cs[(size_t)row * ldc + h * hpitch + col] = acc[i][j][r] + bb;
        }
      } else if (PADZ && col < kCP) {
#pragma unroll
        for (int r = 0; r < 4; ++r) {
          const int row = rbase + i * 16 + (lane >> 4) * 4 + r;
          Cs[(size_t)row * ldc + h * hpitch + col] = 0.f;
        }
      }
    }
  }
}

// ---- tier-D fallback f32 GEMM ----------------------------------------------
template <bool BT, bool BIAS>
__global__ void __launch_bounds__(256) gemm_f32(
    const float* __restrict__ A, const float* __restrict__ B,
    float* __restrict__ Cp, const float* __restrict__ bias, const int M,
    const int N, const int K, const int lda, const int ldb, const int ldc,
    const int hstride) {
  constexpr int BM = 128, BN = 64, BK = 16;
  __shared__ float As[BK][BM + 4];
  __shared__ float Bs[BK][BN + 4];
  const int hoff = blockIdx.z * hstride;
  const int m0 = blockIdx.y * BM, n0 = blockIdx.x * BN;
  const int tid = threadIdx.x;
  const int ty = tid >> 4, tx = tid & 15;
  float acc[8][4];
#pragma unroll
  for (int r = 0; r < 8; ++r)
#pragma unroll
    for (int c = 0; c < 4; ++c) acc[r][c] = 0.f;
  for (int k0 = 0; k0 < K; k0 += BK) {
#pragma unroll
    for (int p = 0; p < 8; ++p) {
      const int idx = tid + p * 256;
      const int mm = idx >> 4, kk = idx & 15;
      float v = 0.f;
      if (k0 + kk < K) v = A[(size_t)(m0 + mm) * lda + hoff + k0 + kk];
      As[kk][mm] = v;
    }
    if (BT) {
#pragma unroll
      for (int p = 0; p < 4; ++p) {
        const int idx = tid + p * 256;
        const int jj = idx >> 4, kk = idx & 15;
        float v = 0.f;
        if ((n0 + jj) < N && (k0 + kk) < K)
          v = B[(size_t)(n0 + jj) * ldb + hoff + k0 + kk];
        Bs[kk][jj] = v;
      }
    } else {
#pragma unroll
      for (int p = 0; p < 4; ++p) {
        const int idx = tid + p * 256;
        const int kk = idx >> 6, jj = idx & 63;
        float v = 0.f;
        if ((n0 + jj) < N && (k0 + kk) < K)
          v = B[(size_t)(k0 + kk) * ldb + hoff + n0 + jj];
        Bs[kk][jj] = v;
      }
    }
    __syncthreads();
#pragma unroll
    for (int kk = 0; kk < BK; ++kk) {
      float a[8], b[4];
#pragma unroll
      for (int r = 0; r < 8; ++r) a[r] = As[kk][ty * 8 + r];
#pragma unroll
      for (int c = 0; c < 4; ++c) b[c] = Bs[kk][tx * 4 + c];
#pragma unroll
      for (int r = 0; r < 8; ++r)
#pragma unroll
        for (int c = 0; c < 4; ++c) acc[r][c] = fmaf(a[r], b[c], acc[r][c]);
    }
    __syncthreads();
  }
#pragma unroll
  for (int r = 0; r < 8; ++r) {
    const int mm = m0 + ty * 8 + r;
    if (mm >= M) continue;
#pragma unroll
    for (int c = 0; c < 4; ++c) {
      const int jj = n0 + tx * 4 + c;
      if (jj < N) {
        float v = acc[r][c];
        if (BIAS) v += bias[hoff + jj];
        Cp[(size_t)mm * ldc + hoff + jj] = v;
      }
    }
  }
}

// ---------------------------------------------------------------------------
extern "C" void kernel_launch(void* const* d_in, const int* in_sizes, int n_in,
                              void* d_out, int out_size, void* d_ws,
                              size_t ws_size, hipStream_t stream) {
  const float* imgf = (const float*)d_in[0];
  const float* c2w = (const float*)d_in[2];
  const float* Kin = (const float*)d_in[3];
  const float* qpl[3] = {(const float*)d_in[5], (const float*)d_in[6],
                         (const float*)d_in[7]};
  const float* Wk = (const float*)d_in[8];
  const float* bk = (const float*)d_in[9];
  const float* Wv = (const float*)d_in[10];
  const float* bv = (const float*)d_in[11];
  const float* ln_g = (const float*)d_in[12];
  const float* ln_b = (const float*)d_in[13];
  float* out = (float*)d_out;
  char* wsb = (char*)d_ws;

  const size_t IMGT_FLOATS = (size_t)kNV * kIMS2;
  const size_t W_ELEMS = (size_t)3 * kBROWS * kKP;

  // layout for NS slots
  auto plan = [&](int NS, bool withImgt, size_t* o, size_t* need) {
    size_t off = 0;
    auto take = [&](size_t bytes) {
      size_t p = off;
      off = (off + bytes + 511) & ~(size_t)511;
      return p;
    };
    o[0] = take(64 * 4);                                 // w2c
    o[1] = take((size_t)NS * kNPIX * 3 * 4);             // qbk
    o[2] = take((size_t)NS * kQKB_FLOATS * 4);           // qkb
    o[3] = take(W_ELEMS * 2);                            // wkhi
    o[4] = take(W_ELEMS * 2);                            // wklo
    o[5] = take(W_ELEMS * 2);                            // wvthi
    o[6] = take(W_ELEMS * 2);                            // wvtlo
    o[7] = take((size_t)NS * kA_ELEMS * 2);              // ahi
    o[8] = take((size_t)NS * kA_ELEMS * 2);              // alo
    o[9] = withImgt ? take(IMGT_FLOATS * 4) : 0;         // imgt
    *need = off;
  };

  size_t o3[10], need3, o1[10], need1, o1s[10], need1s;
  plan(3, true, o3, &need3);
  plan(1, true, o1, &need1);
  plan(1, false, o1s, &need1s);

  const int tier = (ws_size >= need3) ? 0
                   : (ws_size >= need1) ? 1
                   : (ws_size >= need1s) ? 2 : 3;

  if (tier <= 2) {
    const size_t* o = (tier == 0) ? o3 : (tier == 1) ? o1 : o1s;
    float* w2c = (float*)(wsb + o[0]);
    float* qbk = (float*)(wsb + o[1]);
    float* qkb = (float*)(wsb + o[2]);
    unsigned short* wkhi = (unsigned short*)(wsb + o[3]);
    unsigned short* wklo = (unsigned short*)(wsb + o[4]);
    unsigned short* wvthi = (unsigned short*)(wsb + o[5]);
    unsigned short* wvtlo = (unsigned short*)(wsb + o[6]);
    unsigned short* ahi = (unsigned short*)(wsb + o[7]);
    unsigned short* alo = (unsigned short*)(wsb + o[8]);
    float* imgt = (float*)(wsb + o[9]);

    invert4_kernel<<<1, 64, 0, stream>>>(c2w, w2c);
    prep_wk_kernel<<<dim3(kBROWS, 3), 256, 0, stream>>>(Wk, wkhi, wklo);
    prep_wvt_kernel<<<dim3(13, 14, 3), 256, 0, stream>>>(Wv, wvthi, wvtlo);
    if (tier <= 1)
      transpose_img_kernel<<<dim3(64, kNV), 256, 0, stream>>>(imgf, imgt);

    if (tier == 0) {
      // fully batched: 4 big dispatches
      build_q_kernel<true><<<dim3(kNPIX, 3), 256, 0, stream>>>(
          qpl[0], qpl[1], qpl[2], 0, ln_g, ln_b, bk, nullptr, ahi, alo, qbk);
      gemm_mfma<false, true><<<dim3(7, 32, 9), 256, 0, stream>>>(
          ahi, alo, wkhi, wklo, qkb, nullptr, kLDQ, kCP, kQKB_FLOATS);
      sample_attn2_kernel<<<dim3(kNPIX, 3), 256, 0, stream>>>(
          imgt, w2c, Kin, qkb, qbk, 0, ahi, alo);
      gemm_mfma<true, false><<<dim3(7, 32, 9), 256, 0, stream>>>(
          ahi, alo, wvthi, wvtlo, out, bv, kQD, kC, kQN_FLOATS);
    } else {
      for (int p = 0; p < 3; ++p) {
        build_q_kernel<true><<<dim3(kNPIX, 1), 256, 0, stream>>>(
            qpl[0], qpl[1], qpl[2], p, ln_g, ln_b, bk, nullptr, ahi, alo, qbk);
        gemm_mfma<false, true><<<dim3(7, 32, 3), 256, 0, stream>>>(
            ahi, alo, wkhi, wklo, qkb, nullptr, kLDQ, kCP, kQKB_FLOATS);
        if (tier == 1) {
          sample_attn2_kernel<<<dim3(kNPIX, 1), 256, 0, stream>>>(
              imgt, w2c, Kin, qkb, qbk, p, ahi, alo);
        } else {
          sample_attn_kernel<true><<<kNPIX, 256, 0, stream>>>(
              imgf, 1, kG * kG, w2c, Kin, qkb, kLDQ, kCP, qbk, p, nullptr,
              ahi, alo);
        }
        gemm_mfma<true, false><<<dim3(7, 32, 3), 256, 0, stream>>>(
            ahi, alo, wvthi, wvtlo, out + (size_t)p * kQN_FLOATS, bv, kQD, kC,
            kQN_FLOATS);
      }
    }
  } else {
    // tier D: f32 fallback
    float* ws = (float*)d_ws;
    const size_t OFF_QBK = 64;
    const size_t OFF_BIG = OFF_QBK + (size_t)kNPIX * 3;
    float* w2c = ws;
    float* qbk = ws + OFF_QBK;
    float* qn = ws + OFF_BIG;
    float* qkb = qn + kQN_FLOATS;

    invert4_kernel<<<1, 64, 0, stream>>>(c2w, w2c);
    for (int p = 0; p < 3; ++p) {
      build_q_kernel<false><<<dim3(kNPIX, 1), 256, 0, stream>>>(
          qpl[0], qpl[1], qpl[2], p, ln_g, ln_b, bk, qn, nullptr, nullptr,
          qbk);
      gemm_f32<true, false><<<dim3(13, 32, 3), 256, 0, stream>>>(
          qn, Wk, qkb, nullptr, kNPIX, kC, kC, kQD, kQD, kQD, kC);
      sample_attn_kernel<false><<<kNPIX, 256, 0, stream>>>(
          imgf, 1, kG * kG, w2c, Kin, qkb, kQD, kC, qbk, p, qn, nullptr,
          nullptr);
      gemm_f32<false, true><<<dim3(13, 32, 3), 256, 0, stream>>>(
          qn, Wv, out + (size_t)p * kQN_FLOATS, bv, kNPIX, kC, kC, kQD, kQD,
          kQD, kC);
    }
  }
}